// Round 4
// baseline (91.081 us; speedup 1.0000x reference)
//
#include <hip/hip_runtime.h>
#include <math.h>

#define NBC   16          // b*2
#define NF    160
#define NT    1000
#define NTQ   1003        // t rows incl. 3 pad rows at front
#define WSTR  164         // Wt row stride (floats): 164*4=656B = 16B*41 -> b128-aligned rows

// ---------------------------------------------------------------------------
// k1: fused  P = ql_w @ (sgn*far)  ->  LayerNorm -> *sigmoid(q_vec)
//     writes Qn[bc][tt][f], tt = t+3 (rows 0..2 = padded LN(ql_b) rows)
// block: 512 thr = 8 waves (each wave one 20-row fo group) x 64 t
// ---------------------------------------------------------------------------
__global__ __launch_bounds__(512) void k1_qproj_ln(const float* __restrict__ far,
                                                   const float* __restrict__ qlw,
                                                   const float* __restrict__ qlb,
                                                   const float* __restrict__ qng,
                                                   const float* __restrict__ qnb,
                                                   const float* __restrict__ qvec,
                                                   float* __restrict__ Qn) {
    __shared__ float Ws[NF * WSTR];   // Wt[fi][fo]
    __shared__ float Xs[NF * 65];     // X[fi][tl], padded stride 65
    __shared__ float red_s[8 * 64];
    __shared__ float red_q[8 * 64];

    const int bc = blockIdx.x;      // 0..15
    const int t0 = blockIdx.y * 64; // 0..960
    const int tid = threadIdx.x;
    const float sgn = (bc & 1) ? -1.f : 1.f;
    const float* Xb = far + (size_t)bc * NF * NT;

    // stage Wt[fi][fo] = qlw[fo][fi]  (coalesced global reads, 50/thread)
    #pragma unroll
    for (int i = 0; i < 50; ++i) {
        int o = tid + i * 512;          // 0..25599
        int fo = o / 160;
        int fi = o - fo * 160;
        Ws[fi * WSTR + fo] = qlw[o];
    }

    // stage X tile (160 f x 64 t), sign applied
    #pragma unroll
    for (int i = 0; i < 20; ++i) {
        int o = tid + i * 512;
        int fi = o >> 6, tl0 = o & 63;
        int t = t0 + tl0;
        float v = (t < NT) ? Xb[fi * NT + t] : 0.f;
        Xs[fi * 65 + tl0] = v * sgn;
    }
    __syncthreads();

    const int g = __builtin_amdgcn_readfirstlane(tid >> 6); // wave id 0..7
    const int tl = tid & 63;
    const int fo0 = g * 20;

    float acc[20];
    #pragma unroll
    for (int u = 0; u < 20; ++u) acc[u] = 0.f;

    #pragma unroll 4
    for (int fi = 0; fi < NF; ++fi) {
        float x = Xs[fi * 65 + tl];
        const float* wrow = &Ws[fi * WSTR + fo0];
        float4 w0 = *(const float4*)(wrow + 0);
        float4 w1 = *(const float4*)(wrow + 4);
        float4 w2 = *(const float4*)(wrow + 8);
        float4 w3 = *(const float4*)(wrow + 12);
        float4 w4 = *(const float4*)(wrow + 16);
        acc[0]  = fmaf(w0.x, x, acc[0]);
        acc[1]  = fmaf(w0.y, x, acc[1]);
        acc[2]  = fmaf(w0.z, x, acc[2]);
        acc[3]  = fmaf(w0.w, x, acc[3]);
        acc[4]  = fmaf(w1.x, x, acc[4]);
        acc[5]  = fmaf(w1.y, x, acc[5]);
        acc[6]  = fmaf(w1.z, x, acc[6]);
        acc[7]  = fmaf(w1.w, x, acc[7]);
        acc[8]  = fmaf(w2.x, x, acc[8]);
        acc[9]  = fmaf(w2.y, x, acc[9]);
        acc[10] = fmaf(w2.z, x, acc[10]);
        acc[11] = fmaf(w2.w, x, acc[11]);
        acc[12] = fmaf(w3.x, x, acc[12]);
        acc[13] = fmaf(w3.y, x, acc[13]);
        acc[14] = fmaf(w3.z, x, acc[14]);
        acc[15] = fmaf(w3.w, x, acc[15]);
        acc[16] = fmaf(w4.x, x, acc[16]);
        acc[17] = fmaf(w4.y, x, acc[17]);
        acc[18] = fmaf(w4.z, x, acc[18]);
        acc[19] = fmaf(w4.w, x, acc[19]);
    }

    // per-wave LN partials from registers (v = acc + ql_b)
    float ps = 0.f, pq = 0.f;
    #pragma unroll
    for (int u = 0; u < 20; ++u) {
        float vu = acc[u] + qlb[fo0 + u];
        acc[u] = vu;
        ps += vu;
        pq = fmaf(vu, vu, pq);
    }
    red_s[g * 64 + tl] = ps;
    red_q[g * 64 + tl] = pq;
    __syncthreads();   // also guarantees all waves finished reading Xs

    float s = 0.f, q = 0.f;
    #pragma unroll
    for (int gg = 0; gg < 8; ++gg) {
        s += red_s[gg * 64 + tl];
        q += red_q[gg * 64 + tl];
    }
    float mean = s * (1.f / NF);
    float var  = q * (1.f / NF) - mean * mean;
    float inv  = 1.f / sqrtf(var + 1e-5f);

    // normalize in registers, park transposed tile in Xs
    #pragma unroll
    for (int u = 0; u < 20; ++u) {
        int fo = fo0 + u;
        float sq = 1.f / (1.f + expf(-qvec[fo]));
        Xs[fo * 65 + tl] = ((acc[u] - mean) * inv * qng[fo] + qnb[fo]) * sq;
    }
    __syncthreads();

    // coalesced write-out: Qn[bc][t+3][f], runs of 160 floats
    #pragma unroll
    for (int i = 0; i < 20; ++i) {
        int o = tid + i * 512;          // 0..10239
        int ttl = o / 160;              // 0..63
        int f = o - ttl * 160;
        int t = t0 + ttl;
        if (t < NT)
            Qn[((size_t)bc * NTQ + t + 3) * NF + f] = Xs[f * 65 + ttl];
    }

    // padded rows tt = 0..2  (input row = zeros -> LN(ql_b))
    if (t0 == 0 && tid < 3 * NF) {
        int ttp = tid / 160;
        int f = tid - ttp * 160;
        float s2 = 0.f, q2 = 0.f;
        for (int j = 0; j < NF; ++j) {
            float vj = qlb[j];
            s2 += vj;
            q2 = fmaf(vj, vj, q2);
        }
        float mn = s2 * (1.f / NF);
        float vr = q2 * (1.f / NF) - mn * mn;
        float iv = 1.f / sqrtf(vr + 1e-5f);
        float sq = 1.f / (1.f + expf(-qvec[f]));
        Qn[((size_t)bc * NTQ + ttp) * NF + f] = ((qlb[f] - mn) * iv * qng[f] + qnb[f]) * sq;
    }
}

// ---------------------------------------------------------------------------
// k3 (tiled): block per (bc, 64-t tile). mix + Qn staged in LDS (coalesced),
// then identical per-site math: keys, scores, softmax -> W[site][16].
// 8 waves x 8 sites each.
// ---------------------------------------------------------------------------
#define TS 64
#define QSTR 161          // Qs row stride (odd -> conflict-friendly)

__global__ __launch_bounds__(512) void k3_attn_tiled(const float* __restrict__ mix,
                                                     const float* __restrict__ Qn,
                                                     const float* __restrict__ kcw,
                                                     const float* __restrict__ kcb,
                                                     const float* __restrict__ klw,
                                                     const float* __restrict__ klb,
                                                     const float* __restrict__ kng,
                                                     const float* __restrict__ knb,
                                                     const float* __restrict__ kvec,
                                                     float* __restrict__ W) {
    __shared__ float mixS[2 * NF * 65];   // [ch][f][tl], stride 65
    __shared__ float Qs[(TS + 3) * QSTR]; // rows t0..t0+66, [row][f]

    const int bc = blockIdx.x;        // 0..15
    const int t0 = blockIdx.y * TS;   // 0..960
    const int b = bc >> 1, c = bc & 1;
    const int tid = threadIdx.x;

    // ---- stage mix (both channels of batch b), cols t0..t0+63 ----
    const float* mixg = mix + (size_t)(b * 2) * NF * NT;
    if (t0 + TS <= NT) {
        // full tile: float4 path (5120 float4 / 512 thr = 10 iters)
        #pragma unroll
        for (int i = 0; i < 10; ++i) {
            int idx4 = tid + i * 512;
            int ch = idx4 / 2560;
            int rem = idx4 - ch * 2560;
            int f = rem >> 4;
            int t4 = rem & 15;
            float4 v = *(const float4*)(mixg + ((size_t)ch * NF + f) * NT + t0 + 4 * t4);
            float* dst = &mixS[(ch * NF + f) * 65 + 4 * t4];
            dst[0] = v.x; dst[1] = v.y; dst[2] = v.z; dst[3] = v.w;
        }
    } else {
        // edge tile: scalar with clamp (values past NT-1 unused)
        #pragma unroll
        for (int i = 0; i < 40; ++i) {
            int idx = tid + i * 512;
            int ch = idx / 10240;
            int rem = idx - ch * 10240;
            int f = rem >> 6;
            int tl0 = rem & 63;
            int t = t0 + tl0; if (t > NT - 1) t = NT - 1;
            mixS[(ch * NF + f) * 65 + tl0] = mixg[((size_t)ch * NF + f) * NT + t];
        }
    }

    // ---- stage Qn rows t0..t0+66 (2680 float4, 6 iters) ----
    const float* Qg = Qn + (size_t)bc * NTQ * NF;
    #pragma unroll
    for (int i = 0; i < 6; ++i) {
        int idx4 = tid + i * 512;
        if (idx4 < (TS + 3) * 40) {
            int r = idx4 / 40;
            int c4 = idx4 - r * 40;
            int tt = t0 + r; if (tt > NTQ - 1) tt = NTQ - 1;
            float4 v = *(const float4*)(Qg + (size_t)tt * NF + 4 * c4);
            float* dst = &Qs[r * QSTR + 4 * c4];
            dst[0] = v.x; dst[1] = v.y; dst[2] = v.z; dst[3] = v.w;
        }
    }
    __syncthreads();

    // ---- per-wave constants ----
    const int wv = __builtin_amdgcn_readfirstlane(tid >> 6);
    const int lane = tid & 63;

    float kw0[4], kw1[4], kb[4], klwm[16], klbv[4], kngv[4], knbv[4], sigk[4];
    #pragma unroll
    for (int j = 0; j < 4; ++j) {
        kw0[j] = kcw[(4 * c + j) * 2 + 0];
        kw1[j] = kcw[(4 * c + j) * 2 + 1];
        kb[j]  = kcb[4 * c + j];
        klbv[j] = klb[j];
        kngv[j] = kng[j];
        knbv[j] = knb[j];
        sigk[j] = 0.5f / (1.f + expf(-kvec[j]));   // sigmoid(k_vec)/sqrt(k)
    }
    #pragma unroll
    for (int x = 0; x < 16; ++x) klwm[x] = klw[x];

    // ---- 8 sites per wave ----
    for (int so = 0; so < 8; ++so) {
        int ts = wv * 8 + so;
        int t = t0 + ts;
        if (t >= NT) continue;    // wave-uniform

        float s[16];
        #pragma unroll
        for (int x = 0; x < 16; ++x) s[x] = 0.f;

        #pragma unroll
        for (int rep = 0; rep < 3; ++rep) {
            int f = lane + rep * 64;
            if (f < NF) {
                float m0 = mixS[f * 65 + ts];
                float m1 = mixS[(NF + f) * 65 + ts];
                float kraw[4], klin[4];
                #pragma unroll
                for (int j = 0; j < 4; ++j)
                    kraw[j] = fmaf(kw0[j], m0, fmaf(kw1[j], m1, kb[j]));
                #pragma unroll
                for (int jo = 0; jo < 4; ++jo) {
                    float a = klbv[jo];
                    #pragma unroll
                    for (int ji = 0; ji < 4; ++ji) a = fmaf(klwm[jo * 4 + ji], kraw[ji], a);
                    klin[jo] = a;
                }
                float mn = 0.25f * (klin[0] + klin[1] + klin[2] + klin[3]);
                float d0 = klin[0] - mn, d1 = klin[1] - mn, d2 = klin[2] - mn, d3 = klin[3] - mn;
                float var = 0.25f * (d0 * d0 + d1 * d1 + d2 * d2 + d3 * d3);
                float inv = 1.f / sqrtf(var + 1e-5f);
                float kn[4];
                kn[0] = (d0 * inv * kngv[0] + knbv[0]) * sigk[0];
                kn[1] = (d1 * inv * kngv[1] + knbv[1]) * sigk[1];
                kn[2] = (d2 * inv * kngv[2] + knbv[2]) * sigk[2];
                kn[3] = (d3 * inv * kngv[3] + knbv[3]) * sigk[3];

                float q0 = Qs[(ts + 0) * QSTR + f];
                float q1 = Qs[(ts + 1) * QSTR + f];
                float q2 = Qs[(ts + 2) * QSTR + f];
                float q3 = Qs[(ts + 3) * QSTR + f];
                #pragma unroll
                for (int j = 0; j < 4; ++j) {
                    s[0 * 4 + j] = fmaf(q0, kn[j], s[0 * 4 + j]);
                    s[1 * 4 + j] = fmaf(q1, kn[j], s[1 * 4 + j]);
                    s[2 * 4 + j] = fmaf(q2, kn[j], s[2 * 4 + j]);
                    s[3 * 4 + j] = fmaf(q3, kn[j], s[3 * 4 + j]);
                }
            }
        }

        #pragma unroll
        for (int off = 1; off < 64; off <<= 1) {
            #pragma unroll
            for (int x = 0; x < 16; ++x) s[x] += __shfl_xor(s[x], off, 64);
        }

        float wv16[16];
        #pragma unroll
        for (int i = 0; i < 4; ++i) {
            float a = s[i * 4 + 0], b2 = s[i * 4 + 1], c2 = s[i * 4 + 2], d2 = s[i * 4 + 3];
            float mx = fmaxf(fmaxf(a, b2), fmaxf(c2, d2));
            float e0 = expf(a - mx), e1 = expf(b2 - mx), e2 = expf(c2 - mx), e3 = expf(d2 - mx);
            float inv = 1.f / (e0 + e1 + e2 + e3);
            wv16[i * 4 + 0] = e0 * inv;
            wv16[i * 4 + 1] = e1 * inv;
            wv16[i * 4 + 2] = e2 * inv;
            wv16[i * 4 + 3] = e3 * inv;
        }
        if (lane < 16) {
            float v = 0.f;
            #pragma unroll
            for (int x = 0; x < 16; ++x) v = (lane == x) ? wv16[x] : v;
            W[((size_t)bc * NT + t) * 16 + lane] = v;
        }
    }
}

// ---------------------------------------------------------------------------
// complex 4x4 solve, partial pivoting (cabs1), fully unrolled
// ---------------------------------------------------------------------------
__device__ __forceinline__ void csolve4(float Ar[16], float Ai[16],
                                        float br[4], float bi[4],
                                        float wr[4], float wi[4]) {
    #pragma unroll
    for (int col = 0; col < 4; ++col) {
        #pragma unroll
        for (int r = col + 1; r < 4; ++r) {
            float cp = fabsf(Ar[col * 4 + col]) + fabsf(Ai[col * 4 + col]);
            float cr = fabsf(Ar[r * 4 + col]) + fabsf(Ai[r * 4 + col]);
            bool sw = cr > cp;
            #pragma unroll
            for (int m = col; m < 4; ++m) {
                float a0 = Ar[col * 4 + m], a1 = Ar[r * 4 + m];
                Ar[col * 4 + m] = sw ? a1 : a0;
                Ar[r * 4 + m]   = sw ? a0 : a1;
                float c0 = Ai[col * 4 + m], c1 = Ai[r * 4 + m];
                Ai[col * 4 + m] = sw ? c1 : c0;
                Ai[r * 4 + m]   = sw ? c0 : c1;
            }
            float b0 = br[col], b1 = br[r];
            br[col] = sw ? b1 : b0; br[r] = sw ? b0 : b1;
            float d0 = bi[col], d1 = bi[r];
            bi[col] = sw ? d1 : d0; bi[r] = sw ? d0 : d1;
        }
        float pr = Ar[col * 4 + col], pi = Ai[col * 4 + col];
        float den = 1.f / (pr * pr + pi * pi);
        #pragma unroll
        for (int r = col + 1; r < 4; ++r) {
            float nr = Ar[r * 4 + col], ni = Ai[r * 4 + col];
            float fr = (nr * pr + ni * pi) * den;
            float fi = (ni * pr - nr * pi) * den;
            #pragma unroll
            for (int m = col + 1; m < 4; ++m) {
                float tr = Ar[col * 4 + m], ti = Ai[col * 4 + m];
                Ar[r * 4 + m] -= fr * tr - fi * ti;
                Ai[r * 4 + m] -= fr * ti + fi * tr;
            }
            float tr = br[col], ti = bi[col];
            br[r] -= fr * tr - fi * ti;
            bi[r] -= fr * ti + fi * tr;
        }
    }
    #pragma unroll
    for (int col = 3; col >= 0; --col) {
        float sr = br[col], si = bi[col];
        #pragma unroll
        for (int m = col + 1; m < 4; ++m) {
            float tr = Ar[col * 4 + m], ti = Ai[col * 4 + m];
            sr -= tr * wr[m] - ti * wi[m];
            si -= tr * wi[m] + ti * wr[m];
        }
        float pr = Ar[col * 4 + col], pi = Ai[col * 4 + col];
        float den = 1.f / (pr * pr + pi * pi);
        wr[col] = (sr * pr + si * pi) * den;
        wi[col] = (si * pr - sr * pi) * den;
    }
}

// ---------------------------------------------------------------------------
// k4: per (b,f,t): build rank-1 value/out, assemble A,rhs, solve, Wiener sum
// ---------------------------------------------------------------------------
__global__ __launch_bounds__(256) void k4_final(const float* __restrict__ far,
                                                const float* __restrict__ mix,
                                                const float* __restrict__ Wt,
                                                const float* __restrict__ vvec,
                                                float* __restrict__ out) {
    const int t = blockIdx.x * 256 + threadIdx.x;
    const int f = blockIdx.y;
    const int b = blockIdx.z;
    if (t >= NT) return;

    const float* fr  = far + (size_t)(b * 2 + 0) * NF * NT + (size_t)f * NT;
    const float* fim = far + (size_t)(b * 2 + 1) * NF * NT + (size_t)f * NT;
    float ur[4], ui[4];
    #pragma unroll
    for (int d = 0; d < 4; ++d) {
        int tp = t - 3 + d;
        bool ok = tp >= 0;
        ur[d] = ok ? fr[tp] : 0.f;
        ui[d] = ok ? fim[tp] : 0.f;
    }
    float m0 = mix[(size_t)(b * 2 + 0) * NF * NT + (size_t)f * NT + t];
    float m1 = mix[(size_t)(b * 2 + 1) * NF * NT + (size_t)f * NT + t];

    float sv[4];
    #pragma unroll
    for (int i = 0; i < 4; ++i) sv[i] = 1.f / (1.f + expf(-vvec[i]));

    const float* w0p = Wt + ((size_t)(b * 2 + 0) * NT + t) * 16;
    const float* w1p = Wt + ((size_t)(b * 2 + 1) * NT + t) * 16;

    float g0[4], g1[4];
    #pragma unroll
    for (int j = 0; j < 4; ++j) { g0[j] = 0.f; g1[j] = 0.f; }
    #pragma unroll
    for (int i = 0; i < 4; ++i) {
        float a0 = ur[i] * sv[i];
        float a1 = -ui[i] * sv[i];
        #pragma unroll
        for (int j = 0; j < 4; ++j) {
            g0[j] = fmaf(a0, w0p[i * 4 + j], g0[j]);
            g1[j] = fmaf(a1, w1p[i * 4 + j], g1[j]);
        }
    }

    float Ar[16], Ai[16], br[4], bi[4], wr[4], wi[4];
    #pragma unroll
    for (int j = 0; j < 4; ++j) {
        #pragma unroll
        for (int m = 0; m < 4; ++m) {
            float e = (j == m) ? (1.0f + 1e-8f) : 1e-8f;
            Ar[j * 4 + m] = fmaf(ur[m], g0[j], e);
            Ai[j * 4 + m] = fmaf(-ui[m], g1[j], e);
        }
        br[j] = m0 * g0[j];
        bi[j] = m1 * g1[j];
    }

    csolve4(Ar, Ai, br, bi, wr, wi);

    float resr = 0.f, resi = 0.f;
    #pragma unroll
    for (int d = 0; d < 4; ++d) {
        resr += ur[d] * wr[d] - ui[d] * wi[d];
        resi += ur[d] * wi[d] + ui[d] * wr[d];
    }
    out[(size_t)(b * 2 + 0) * NF * NT + (size_t)f * NT + t] = resr;
    out[(size_t)(b * 2 + 1) * NF * NT + (size_t)f * NT + t] = resi;
}

// ---------------------------------------------------------------------------
extern "C" void kernel_launch(void* const* d_in, const int* in_sizes, int n_in,
                              void* d_out, int out_size, void* d_ws, size_t ws_size,
                              hipStream_t stream) {
    const float* far  = (const float*)d_in[0];
    const float* mix  = (const float*)d_in[1];
    const float* kcw  = (const float*)d_in[2];
    const float* kcb  = (const float*)d_in[3];
    const float* qlw  = (const float*)d_in[4];
    const float* qlb  = (const float*)d_in[5];
    const float* qng  = (const float*)d_in[6];
    const float* qnb  = (const float*)d_in[7];
    const float* klw  = (const float*)d_in[8];
    const float* klb  = (const float*)d_in[9];
    const float* kng  = (const float*)d_in[10];
    const float* knb  = (const float*)d_in[11];
    const float* qvec = (const float*)d_in[12];
    const float* kvec = (const float*)d_in[13];
    const float* vvec = (const float*)d_in[14];

    float* Qn = (float*)d_ws;                       // 16*1003*160
    float* W  = Qn + (size_t)NBC * NTQ * NF;        // 16*1000*16
    float* out = (float*)d_out;

    k1_qproj_ln<<<dim3(NBC, 16), 512, 0, stream>>>(far, qlw, qlb, qng, qnb, qvec, Qn);
    k3_attn_tiled<<<dim3(NBC, 16), 512, 0, stream>>>(mix, Qn, kcw, kcb, klw, klb,
                                                     kng, knb, kvec, W);
    k4_final<<<dim3(4, NF, 8), 256, 0, stream>>>(far, mix, W, vvec, out);
}

// Round 5
// 78.634 us; speedup vs baseline: 1.1583x; 1.1583x over previous
//
#include <hip/hip_runtime.h>
#include <math.h>

#define NBC   16          // b*2
#define NF    160
#define NT    1000
#define NTP   1040        // Qn t-stride (padded; u index = t+3, u in [0,1003))

typedef __attribute__((ext_vector_type(8))) short short8;
typedef __attribute__((ext_vector_type(4))) float f32x4;

static __device__ __forceinline__ short f2bf(float x) {
    unsigned u = __builtin_bit_cast(unsigned, x);
    unsigned r = (u + 0x7fffu + ((u >> 16) & 1u)) >> 16;
    return (short)r;
}
static __device__ __forceinline__ float bf2f(short s) {
    unsigned u = ((unsigned)(unsigned short)s) << 16;
    return __builtin_bit_cast(float, u);
}

// ---------------------------------------------------------------------------
// k1 (MFMA): P = ql_w @ (sgn*far) via split-bf16 mfma_f32_16x16x32_bf16,
// then LayerNorm over fo + *sigmoid(q_vec); writes Qn[bc][f][u], u = t+3.
// Block: 640 thr = 10 waves; wave w owns fo rows [16w,16w+16), W-fragments
// live in VGPRs (hi/lo), X streams as B-fragments from LDS. Grid (16,16).
// ---------------------------------------------------------------------------
__global__ __launch_bounds__(640) void k1_mfma_ln(const float* __restrict__ far,
                                                  const float* __restrict__ qlw,
                                                  const float* __restrict__ qlb,
                                                  const float* __restrict__ qng,
                                                  const float* __restrict__ qnb,
                                                  const float* __restrict__ qvec,
                                                  float* __restrict__ Qn) {
    __shared__ float Xs[NF * 66];          // fp32 stage, stride 66
    __shared__ short Bhi[5 * 4 * 64 * 8];  // B fragments hi (bf16)
    __shared__ short Blo[5 * 4 * 64 * 8];  // B fragments lo
    __shared__ float redS[64 * 41];
    __shared__ float redQ[64 * 41];
    __shared__ float lnM[64], lnI[64];

    const int bc = blockIdx.x;
    const int t0 = blockIdx.y * 64;
    const int tid = threadIdx.x;
    const float sgn = (bc & 1) ? -1.f : 1.f;
    const float* Xb = far + (size_t)bc * NF * NT;

    const int w = __builtin_amdgcn_readfirstlane(tid >> 6);  // wave 0..9
    const int l = tid & 63;
    const int row = l & 15;        // A row / D col
    const int kb = l >> 4;         // k-block 0..3

    // ---- A fragments (weights) -> registers, hi/lo bf16 ----
    short8 Ahi[5], Alo[5];
    #pragma unroll
    for (int fc = 0; fc < 5; ++fc) {
        const float* ap = qlw + (size_t)(16 * w + row) * NF + fc * 32 + kb * 8;
        float4 x0 = *(const float4*)(ap + 0);
        float4 x1 = *(const float4*)(ap + 4);
        float xv[8] = {x0.x, x0.y, x0.z, x0.w, x1.x, x1.y, x1.z, x1.w};
        short8 h, lo;
        #pragma unroll
        for (int j = 0; j < 8; ++j) {
            short hj = f2bf(xv[j]);
            h[j] = hj;
            lo[j] = f2bf(xv[j] - bf2f(hj));
        }
        Ahi[fc] = h; Alo[fc] = lo;
    }

    // ---- stage X fp32 (160 x 64), sign applied ----
    #pragma unroll
    for (int i = 0; i < 16; ++i) {
        int o = tid + i * 640;
        int fi = o >> 6, tl0 = o & 63;
        int t = t0 + tl0;
        Xs[fi * 66 + tl0] = (t < NT) ? Xb[fi * NT + t] * sgn : 0.f;
    }
    __syncthreads();

    // ---- convert to B fragments (hi/lo), fragment-layout LDS ----
    #pragma unroll
    for (int e = 0; e < 2; ++e) {
        int slot = tid * 2 + e;            // (fc*4+tt)*64 + lane
        int sl = slot & 63;
        int g = slot >> 6;                 // fc*4+tt
        int fi0 = (g >> 2) * 32 + ((sl >> 4) << 3);
        int tloc = (g & 3) * 16 + (sl & 15);
        short8 h, lo;
        #pragma unroll
        for (int j = 0; j < 8; ++j) {
            float x = Xs[(fi0 + j) * 66 + tloc];
            short hj = f2bf(x);
            h[j] = hj;
            lo[j] = f2bf(x - bf2f(hj));
        }
        *(short8*)&Bhi[slot * 8] = h;
        *(short8*)&Blo[slot * 8] = lo;
    }
    __syncthreads();

    // ---- MFMA main: acc[tt] = W·X for this wave's 16 fo rows ----
    f32x4 acc0 = {0.f, 0.f, 0.f, 0.f}, acc1 = acc0, acc2 = acc0, acc3 = acc0;
    #pragma unroll
    for (int fc = 0; fc < 5; ++fc) {
        #pragma unroll
        for (int tt = 0; tt < 4; ++tt) {
            short8 bh = *(const short8*)&Bhi[((fc * 4 + tt) * 64 + l) * 8];
            short8 bl = *(const short8*)&Blo[((fc * 4 + tt) * 64 + l) * 8];
            f32x4 a = (tt == 0) ? acc0 : (tt == 1) ? acc1 : (tt == 2) ? acc2 : acc3;
            a = __builtin_amdgcn_mfma_f32_16x16x32_bf16(Ahi[fc], bh, a, 0, 0, 0);
            a = __builtin_amdgcn_mfma_f32_16x16x32_bf16(Ahi[fc], bl, a, 0, 0, 0);
            a = __builtin_amdgcn_mfma_f32_16x16x32_bf16(Alo[fc], bh, a, 0, 0, 0);
            if (tt == 0) acc0 = a; else if (tt == 1) acc1 = a; else if (tt == 2) acc2 = a; else acc3 = a;
        }
    }

    // D layout: col(t) = l&15, row(fo) = kb*4 + reg   [m89-verified]
    float qlbv[4], qngv[4], qnbv[4], sgqv[4];
    #pragma unroll
    for (int r = 0; r < 4; ++r) {
        int fo = 16 * w + kb * 4 + r;
        qlbv[r] = qlb[fo];
        qngv[r] = qng[fo];
        qnbv[r] = qnb[fo];
        sgqv[r] = 1.f / (1.f + expf(-qvec[fo]));
    }

    // LN partials: per tt, 4 fo values at t = tt*16 + (l&15)
    #pragma unroll
    for (int tt = 0; tt < 4; ++tt) {
        f32x4 a = (tt == 0) ? acc0 : (tt == 1) ? acc1 : (tt == 2) ? acc2 : acc3;
        float v0 = a[0] + qlbv[0], v1 = a[1] + qlbv[1];
        float v2 = a[2] + qlbv[2], v3 = a[3] + qlbv[3];
        float ps = v0 + v1 + v2 + v3;
        float pq = v0 * v0 + v1 * v1 + v2 * v2 + v3 * v3;
        int tl = tt * 16 + (l & 15);
        redS[tl * 41 + w * 4 + kb] = ps;
        redQ[tl * 41 + w * 4 + kb] = pq;
    }
    __syncthreads();

    if (tid < 64) {
        float s = 0.f, q = 0.f;
        #pragma unroll 8
        for (int j = 0; j < 40; ++j) {
            s += redS[tid * 41 + j];
            q += redQ[tid * 41 + j];
        }
        float mean = s * (1.f / NF);
        float var = q * (1.f / NF) - mean * mean;
        lnM[tid] = mean;
        lnI[tid] = 1.f / sqrtf(var + 1e-5f);
    }
    __syncthreads();

    float* Qb = Qn + (size_t)bc * NF * NTP;
    #pragma unroll
    for (int tt = 0; tt < 4; ++tt) {
        f32x4 a = (tt == 0) ? acc0 : (tt == 1) ? acc1 : (tt == 2) ? acc2 : acc3;
        int tl = tt * 16 + (l & 15);
        int t = t0 + tl;
        float mean = lnM[tl], inv = lnI[tl];
        if (t < NT) {
            #pragma unroll
            for (int r = 0; r < 4; ++r) {
                int fo = 16 * w + kb * 4 + r;
                float v = a[r] + qlbv[r];
                float vn = ((v - mean) * inv * qngv[r] + qnbv[r]) * sgqv[r];
                Qb[(size_t)fo * NTP + 3 + t] = vn;
            }
        }
    }

    // padded rows u = 0..2 (input = zeros -> LN(ql_b))
    if (t0 == 0 && tid < 3 * NF) {
        int ttp = tid / NF;
        int f = tid - ttp * NF;
        float s2 = 0.f, q2 = 0.f;
        for (int j = 0; j < NF; ++j) {
            float vj = qlb[j];
            s2 += vj;
            q2 = fmaf(vj, vj, q2);
        }
        float mn = s2 * (1.f / NF);
        float vr = q2 * (1.f / NF) - mn * mn;
        float iv = 1.f / sqrtf(vr + 1e-5f);
        float sq = 1.f / (1.f + expf(-qvec[f]));
        Qb[(size_t)f * NTP + ttp] = ((qlb[f] - mn) * iv * qng[f] + qnb[f]) * sq;
    }
}

// ---------------------------------------------------------------------------
// k3 (tiled): block per (bc, 64-t tile). mix + Qn staged in LDS (coalesced),
// then per-site math: keys, scores, softmax -> W[site][16]. 8 waves x 8 sites.
// Qn layout is [bc][f][u] (u = t+3), row stride NTP.
// ---------------------------------------------------------------------------
#define TS 64
#define QSTR 69           // Qs2 row stride (floats)

__global__ __launch_bounds__(512) void k3_attn_tiled(const float* __restrict__ mix,
                                                     const float* __restrict__ Qn,
                                                     const float* __restrict__ kcw,
                                                     const float* __restrict__ kcb,
                                                     const float* __restrict__ klw,
                                                     const float* __restrict__ klb,
                                                     const float* __restrict__ kng,
                                                     const float* __restrict__ knb,
                                                     const float* __restrict__ kvec,
                                                     float* __restrict__ W) {
    __shared__ float mixS[2 * NF * 65];   // [ch][f][tl], stride 65
    __shared__ float Qs2[NF * QSTR];      // [f][j], u = t0 + j, j < 68

    const int bc = blockIdx.x;        // 0..15
    const int t0 = blockIdx.y * TS;   // 0..960
    const int b = bc >> 1, c = bc & 1;
    const int tid = threadIdx.x;

    // ---- stage mix (both channels of batch b), cols t0..t0+63 ----
    const float* mixg = mix + (size_t)(b * 2) * NF * NT;
    if (t0 + TS <= NT) {
        #pragma unroll
        for (int i = 0; i < 10; ++i) {
            int idx4 = tid + i * 512;
            int ch = idx4 / 2560;
            int rem = idx4 - ch * 2560;
            int f = rem >> 4;
            int t4 = rem & 15;
            float4 v = *(const float4*)(mixg + ((size_t)ch * NF + f) * NT + t0 + 4 * t4);
            float* dst = &mixS[(ch * NF + f) * 65 + 4 * t4];
            dst[0] = v.x; dst[1] = v.y; dst[2] = v.z; dst[3] = v.w;
        }
    } else {
        #pragma unroll
        for (int i = 0; i < 40; ++i) {
            int idx = tid + i * 512;
            int ch = idx / 10240;
            int rem = idx - ch * 10240;
            int f = rem >> 6;
            int tl0 = rem & 63;
            int t = t0 + tl0; if (t > NT - 1) t = NT - 1;
            mixS[(ch * NF + f) * 65 + tl0] = mixg[((size_t)ch * NF + f) * NT + t];
        }
    }

    // ---- stage Qn rows: Qs2[f][0..67], u = t0 + j  (17 float4 per f) ----
    const float* Qg = Qn + (size_t)bc * NF * NTP;
    #pragma unroll
    for (int i = 0; i < 6; ++i) {
        int idx4 = tid + i * 512;
        if (idx4 < NF * 17) {
            int f = idx4 / 17;
            int c4 = idx4 - f * 17;
            float4 v = *(const float4*)(Qg + (size_t)f * NTP + t0 + 4 * c4);
            float* dst = &Qs2[f * QSTR + 4 * c4];
            dst[0] = v.x; dst[1] = v.y; dst[2] = v.z; dst[3] = v.w;
        }
    }
    __syncthreads();

    const int wv = __builtin_amdgcn_readfirstlane(tid >> 6);
    const int lane = tid & 63;

    float kw0[4], kw1[4], kb[4], klwm[16], klbv[4], kngv[4], knbv[4], sigk[4];
    #pragma unroll
    for (int j = 0; j < 4; ++j) {
        kw0[j] = kcw[(4 * c + j) * 2 + 0];
        kw1[j] = kcw[(4 * c + j) * 2 + 1];
        kb[j]  = kcb[4 * c + j];
        klbv[j] = klb[j];
        kngv[j] = kng[j];
        knbv[j] = knb[j];
        sigk[j] = 0.5f / (1.f + expf(-kvec[j]));   // sigmoid(k_vec)/sqrt(k)
    }
    #pragma unroll
    for (int x = 0; x < 16; ++x) klwm[x] = klw[x];

    for (int so = 0; so < 8; ++so) {
        int ts = wv * 8 + so;
        int t = t0 + ts;
        if (t >= NT) continue;    // wave-uniform

        float s[16];
        #pragma unroll
        for (int x = 0; x < 16; ++x) s[x] = 0.f;

        #pragma unroll
        for (int rep = 0; rep < 3; ++rep) {
            int f = lane + rep * 64;
            if (f < NF) {
                float m0 = mixS[f * 65 + ts];
                float m1 = mixS[(NF + f) * 65 + ts];
                float kraw[4], klin[4];
                #pragma unroll
                for (int j = 0; j < 4; ++j)
                    kraw[j] = fmaf(kw0[j], m0, fmaf(kw1[j], m1, kb[j]));
                #pragma unroll
                for (int jo = 0; jo < 4; ++jo) {
                    float a = klbv[jo];
                    #pragma unroll
                    for (int ji = 0; ji < 4; ++ji) a = fmaf(klwm[jo * 4 + ji], kraw[ji], a);
                    klin[jo] = a;
                }
                float mn = 0.25f * (klin[0] + klin[1] + klin[2] + klin[3]);
                float d0 = klin[0] - mn, d1 = klin[1] - mn, d2 = klin[2] - mn, d3 = klin[3] - mn;
                float var = 0.25f * (d0 * d0 + d1 * d1 + d2 * d2 + d3 * d3);
                float inv = 1.f / sqrtf(var + 1e-5f);
                float kn[4];
                kn[0] = (d0 * inv * kngv[0] + knbv[0]) * sigk[0];
                kn[1] = (d1 * inv * kngv[1] + knbv[1]) * sigk[1];
                kn[2] = (d2 * inv * kngv[2] + knbv[2]) * sigk[2];
                kn[3] = (d3 * inv * kngv[3] + knbv[3]) * sigk[3];

                float q0 = Qs2[f * QSTR + ts + 0];
                float q1 = Qs2[f * QSTR + ts + 1];
                float q2 = Qs2[f * QSTR + ts + 2];
                float q3 = Qs2[f * QSTR + ts + 3];
                #pragma unroll
                for (int j = 0; j < 4; ++j) {
                    s[0 * 4 + j] = fmaf(q0, kn[j], s[0 * 4 + j]);
                    s[1 * 4 + j] = fmaf(q1, kn[j], s[1 * 4 + j]);
                    s[2 * 4 + j] = fmaf(q2, kn[j], s[2 * 4 + j]);
                    s[3 * 4 + j] = fmaf(q3, kn[j], s[3 * 4 + j]);
                }
            }
        }

        #pragma unroll
        for (int off = 1; off < 64; off <<= 1) {
            #pragma unroll
            for (int x = 0; x < 16; ++x) s[x] += __shfl_xor(s[x], off, 64);
        }

        float wv16[16];
        #pragma unroll
        for (int i = 0; i < 4; ++i) {
            float a = s[i * 4 + 0], b2 = s[i * 4 + 1], c2 = s[i * 4 + 2], d2 = s[i * 4 + 3];
            float mx = fmaxf(fmaxf(a, b2), fmaxf(c2, d2));
            float e0 = expf(a - mx), e1 = expf(b2 - mx), e2 = expf(c2 - mx), e3 = expf(d2 - mx);
            float inv = 1.f / (e0 + e1 + e2 + e3);
            wv16[i * 4 + 0] = e0 * inv;
            wv16[i * 4 + 1] = e1 * inv;
            wv16[i * 4 + 2] = e2 * inv;
            wv16[i * 4 + 3] = e3 * inv;
        }
        if (lane < 16) {
            float v = 0.f;
            #pragma unroll
            for (int x = 0; x < 16; ++x) v = (lane == x) ? wv16[x] : v;
            W[((size_t)bc * NT + t) * 16 + lane] = v;
        }
    }
}

// ---------------------------------------------------------------------------
// complex 4x4 solve, partial pivoting (cabs1), fully unrolled
// ---------------------------------------------------------------------------
__device__ __forceinline__ void csolve4(float Ar[16], float Ai[16],
                                        float br[4], float bi[4],
                                        float wr[4], float wi[4]) {
    #pragma unroll
    for (int col = 0; col < 4; ++col) {
        #pragma unroll
        for (int r = col + 1; r < 4; ++r) {
            float cp = fabsf(Ar[col * 4 + col]) + fabsf(Ai[col * 4 + col]);
            float cr = fabsf(Ar[r * 4 + col]) + fabsf(Ai[r * 4 + col]);
            bool sw = cr > cp;
            #pragma unroll
            for (int m = col; m < 4; ++m) {
                float a0 = Ar[col * 4 + m], a1 = Ar[r * 4 + m];
                Ar[col * 4 + m] = sw ? a1 : a0;
                Ar[r * 4 + m]   = sw ? a0 : a1;
                float c0 = Ai[col * 4 + m], c1 = Ai[r * 4 + m];
                Ai[col * 4 + m] = sw ? c1 : c0;
                Ai[r * 4 + m]   = sw ? c0 : c1;
            }
            float b0 = br[col], b1 = br[r];
            br[col] = sw ? b1 : b0; br[r] = sw ? b0 : b1;
            float d0 = bi[col], d1 = bi[r];
            bi[col] = sw ? d1 : d0; bi[r] = sw ? d0 : d1;
        }
        float pr = Ar[col * 4 + col], pi = Ai[col * 4 + col];
        float den = 1.f / (pr * pr + pi * pi);
        #pragma unroll
        for (int r = col + 1; r < 4; ++r) {
            float nr = Ar[r * 4 + col], ni = Ai[r * 4 + col];
            float fr = (nr * pr + ni * pi) * den;
            float fi = (ni * pr - nr * pi) * den;
            #pragma unroll
            for (int m = col + 1; m < 4; ++m) {
                float tr = Ar[col * 4 + m], ti = Ai[col * 4 + m];
                Ar[r * 4 + m] -= fr * tr - fi * ti;
                Ai[r * 4 + m] -= fr * ti + fi * tr;
            }
            float tr = br[col], ti = bi[col];
            br[r] -= fr * tr - fi * ti;
            bi[r] -= fr * ti + fi * tr;
        }
    }
    #pragma unroll
    for (int col = 3; col >= 0; --col) {
        float sr = br[col], si = bi[col];
        #pragma unroll
        for (int m = col + 1; m < 4; ++m) {
            float tr = Ar[col * 4 + m], ti = Ai[col * 4 + m];
            sr -= tr * wr[m] - ti * wi[m];
            si -= tr * wi[m] + ti * wr[m];
        }
        float pr = Ar[col * 4 + col], pi = Ai[col * 4 + col];
        float den = 1.f / (pr * pr + pi * pi);
        wr[col] = (sr * pr + si * pi) * den;
        wi[col] = (si * pr - sr * pi) * den;
    }
}

// ---------------------------------------------------------------------------
// k4: per (b,f,t): build rank-1 value/out, assemble A,rhs, solve, Wiener sum
// ---------------------------------------------------------------------------
__global__ __launch_bounds__(256) void k4_final(const float* __restrict__ far,
                                                const float* __restrict__ mix,
                                                const float* __restrict__ Wt,
                                                const float* __restrict__ vvec,
                                                float* __restrict__ out) {
    const int t = blockIdx.x * 256 + threadIdx.x;
    const int f = blockIdx.y;
    const int b = blockIdx.z;
    if (t >= NT) return;

    const float* fr  = far + (size_t)(b * 2 + 0) * NF * NT + (size_t)f * NT;
    const float* fim = far + (size_t)(b * 2 + 1) * NF * NT + (size_t)f * NT;
    float ur[4], ui[4];
    #pragma unroll
    for (int d = 0; d < 4; ++d) {
        int tp = t - 3 + d;
        bool ok = tp >= 0;
        ur[d] = ok ? fr[tp] : 0.f;
        ui[d] = ok ? fim[tp] : 0.f;
    }
    float m0 = mix[(size_t)(b * 2 + 0) * NF * NT + (size_t)f * NT + t];
    float m1 = mix[(size_t)(b * 2 + 1) * NF * NT + (size_t)f * NT + t];

    float sv[4];
    #pragma unroll
    for (int i = 0; i < 4; ++i) sv[i] = 1.f / (1.f + expf(-vvec[i]));

    const float* w0p = Wt + ((size_t)(b * 2 + 0) * NT + t) * 16;
    const float* w1p = Wt + ((size_t)(b * 2 + 1) * NT + t) * 16;

    float g0[4], g1[4];
    #pragma unroll
    for (int j = 0; j < 4; ++j) { g0[j] = 0.f; g1[j] = 0.f; }
    #pragma unroll
    for (int i = 0; i < 4; ++i) {
        float a0 = ur[i] * sv[i];
        float a1 = -ui[i] * sv[i];
        #pragma unroll
        for (int j = 0; j < 4; ++j) {
            g0[j] = fmaf(a0, w0p[i * 4 + j], g0[j]);
            g1[j] = fmaf(a1, w1p[i * 4 + j], g1[j]);
        }
    }

    float Ar[16], Ai[16], br[4], bi[4], wr[4], wi[4];
    #pragma unroll
    for (int j = 0; j < 4; ++j) {
        #pragma unroll
        for (int m = 0; m < 4; ++m) {
            float e = (j == m) ? (1.0f + 1e-8f) : 1e-8f;
            Ar[j * 4 + m] = fmaf(ur[m], g0[j], e);
            Ai[j * 4 + m] = fmaf(-ui[m], g1[j], e);
        }
        br[j] = m0 * g0[j];
        bi[j] = m1 * g1[j];
    }

    csolve4(Ar, Ai, br, bi, wr, wi);

    float resr = 0.f, resi = 0.f;
    #pragma unroll
    for (int d = 0; d < 4; ++d) {
        resr += ur[d] * wr[d] - ui[d] * wi[d];
        resi += ur[d] * wi[d] + ui[d] * wr[d];
    }
    out[(size_t)(b * 2 + 0) * NF * NT + (size_t)f * NT + t] = resr;
    out[(size_t)(b * 2 + 1) * NF * NT + (size_t)f * NT + t] = resi;
}

// ---------------------------------------------------------------------------
extern "C" void kernel_launch(void* const* d_in, const int* in_sizes, int n_in,
                              void* d_out, int out_size, void* d_ws, size_t ws_size,
                              hipStream_t stream) {
    const float* far  = (const float*)d_in[0];
    const float* mix  = (const float*)d_in[1];
    const float* kcw  = (const float*)d_in[2];
    const float* kcb  = (const float*)d_in[3];
    const float* qlw  = (const float*)d_in[4];
    const float* qlb  = (const float*)d_in[5];
    const float* qng  = (const float*)d_in[6];
    const float* qnb  = (const float*)d_in[7];
    const float* klw  = (const float*)d_in[8];
    const float* klb  = (const float*)d_in[9];
    const float* kng  = (const float*)d_in[10];
    const float* knb  = (const float*)d_in[11];
    const float* qvec = (const float*)d_in[12];
    const float* kvec = (const float*)d_in[13];
    const float* vvec = (const float*)d_in[14];

    float* Qn = (float*)d_ws;                       // 16*160*NTP
    float* W  = Qn + (size_t)NBC * NF * NTP;        // 16*1000*16
    float* out = (float*)d_out;

    k1_mfma_ln<<<dim3(NBC, 16), 640, 0, stream>>>(far, qlw, qlb, qng, qnb, qvec, Qn);
    k3_attn_tiled<<<dim3(NBC, 16), 512, 0, stream>>>(mix, Qn, kcw, kcb, klw, klb,
                                                     kng, knb, kvec, W);
    k4_final<<<dim3(4, NF, 8), 256, 0, stream>>>(far, mix, W, vvec, out);
}

// Round 6
// 63.771 us; speedup vs baseline: 1.4283x; 1.2331x over previous
//
#include <hip/hip_runtime.h>
#include <math.h>

#define NBC   16          // b*2
#define NF    160
#define NT    1000
#define NTP   1040        // Qn t-stride (padded; u index = t+3, u in [0,1003))

typedef __attribute__((ext_vector_type(8))) short short8;
typedef __attribute__((ext_vector_type(4))) float f32x4;

static __device__ __forceinline__ short f2bf(float x) {
    unsigned u = __builtin_bit_cast(unsigned, x);
    unsigned r = (u + 0x7fffu + ((u >> 16) & 1u)) >> 16;
    return (short)r;
}
static __device__ __forceinline__ float bf2f(short s) {
    unsigned u = ((unsigned)(unsigned short)s) << 16;
    return __builtin_bit_cast(float, u);
}

// ---------------------------------------------------------------------------
// k1 (MFMA): P = ql_w @ (sgn*far) via split-bf16 mfma_f32_16x16x32_bf16,
// then LayerNorm over fo + *sigmoid(q_vec); writes Qn[bc][f][u], u = t+3.
// ---------------------------------------------------------------------------
__global__ __launch_bounds__(640) void k1_mfma_ln(const float* __restrict__ far,
                                                  const float* __restrict__ qlw,
                                                  const float* __restrict__ qlb,
                                                  const float* __restrict__ qng,
                                                  const float* __restrict__ qnb,
                                                  const float* __restrict__ qvec,
                                                  float* __restrict__ Qn) {
    __shared__ float Xs[NF * 66];          // fp32 stage, stride 66
    __shared__ short Bhi[5 * 4 * 64 * 8];  // B fragments hi (bf16)
    __shared__ short Blo[5 * 4 * 64 * 8];  // B fragments lo
    __shared__ float redS[64 * 41];
    __shared__ float redQ[64 * 41];
    __shared__ float lnM[64], lnI[64];

    const int bc = blockIdx.x;
    const int t0 = blockIdx.y * 64;
    const int tid = threadIdx.x;
    const float sgn = (bc & 1) ? -1.f : 1.f;
    const float* Xb = far + (size_t)bc * NF * NT;

    const int w = __builtin_amdgcn_readfirstlane(tid >> 6);  // wave 0..9
    const int l = tid & 63;
    const int row = l & 15;        // A row / D col
    const int kb = l >> 4;         // k-block 0..3

    // ---- A fragments (weights) -> registers, hi/lo bf16 ----
    short8 Ahi[5], Alo[5];
    #pragma unroll
    for (int fc = 0; fc < 5; ++fc) {
        const float* ap = qlw + (size_t)(16 * w + row) * NF + fc * 32 + kb * 8;
        float4 x0 = *(const float4*)(ap + 0);
        float4 x1 = *(const float4*)(ap + 4);
        float xv[8] = {x0.x, x0.y, x0.z, x0.w, x1.x, x1.y, x1.z, x1.w};
        short8 h, lo;
        #pragma unroll
        for (int j = 0; j < 8; ++j) {
            short hj = f2bf(xv[j]);
            h[j] = hj;
            lo[j] = f2bf(xv[j] - bf2f(hj));
        }
        Ahi[fc] = h; Alo[fc] = lo;
    }

    // ---- stage X fp32 (160 x 64), sign applied ----
    #pragma unroll
    for (int i = 0; i < 16; ++i) {
        int o = tid + i * 640;
        int fi = o >> 6, tl0 = o & 63;
        int t = t0 + tl0;
        Xs[fi * 66 + tl0] = (t < NT) ? Xb[fi * NT + t] * sgn : 0.f;
    }
    __syncthreads();

    // ---- convert to B fragments (hi/lo), fragment-layout LDS ----
    #pragma unroll
    for (int e = 0; e < 2; ++e) {
        int slot = tid * 2 + e;            // (fc*4+tt)*64 + lane
        int sl = slot & 63;
        int g = slot >> 6;                 // fc*4+tt
        int fi0 = (g >> 2) * 32 + ((sl >> 4) << 3);
        int tloc = (g & 3) * 16 + (sl & 15);
        short8 h, lo;
        #pragma unroll
        for (int j = 0; j < 8; ++j) {
            float x = Xs[(fi0 + j) * 66 + tloc];
            short hj = f2bf(x);
            h[j] = hj;
            lo[j] = f2bf(x - bf2f(hj));
        }
        *(short8*)&Bhi[slot * 8] = h;
        *(short8*)&Blo[slot * 8] = lo;
    }
    __syncthreads();

    // ---- MFMA main: acc[tt] = W·X for this wave's 16 fo rows ----
    f32x4 acc0 = {0.f, 0.f, 0.f, 0.f}, acc1 = acc0, acc2 = acc0, acc3 = acc0;
    #pragma unroll
    for (int fc = 0; fc < 5; ++fc) {
        #pragma unroll
        for (int tt = 0; tt < 4; ++tt) {
            short8 bh = *(const short8*)&Bhi[((fc * 4 + tt) * 64 + l) * 8];
            short8 bl = *(const short8*)&Blo[((fc * 4 + tt) * 64 + l) * 8];
            f32x4 a = (tt == 0) ? acc0 : (tt == 1) ? acc1 : (tt == 2) ? acc2 : acc3;
            a = __builtin_amdgcn_mfma_f32_16x16x32_bf16(Ahi[fc], bh, a, 0, 0, 0);
            a = __builtin_amdgcn_mfma_f32_16x16x32_bf16(Ahi[fc], bl, a, 0, 0, 0);
            a = __builtin_amdgcn_mfma_f32_16x16x32_bf16(Alo[fc], bh, a, 0, 0, 0);
            if (tt == 0) acc0 = a; else if (tt == 1) acc1 = a; else if (tt == 2) acc2 = a; else acc3 = a;
        }
    }

    // D layout: col(t) = l&15, row(fo) = kb*4 + reg
    float qlbv[4], qngv[4], qnbv[4], sgqv[4];
    #pragma unroll
    for (int r = 0; r < 4; ++r) {
        int fo = 16 * w + kb * 4 + r;
        qlbv[r] = qlb[fo];
        qngv[r] = qng[fo];
        qnbv[r] = qnb[fo];
        sgqv[r] = 1.f / (1.f + expf(-qvec[fo]));
    }

    #pragma unroll
    for (int tt = 0; tt < 4; ++tt) {
        f32x4 a = (tt == 0) ? acc0 : (tt == 1) ? acc1 : (tt == 2) ? acc2 : acc3;
        float v0 = a[0] + qlbv[0], v1 = a[1] + qlbv[1];
        float v2 = a[2] + qlbv[2], v3 = a[3] + qlbv[3];
        float ps = v0 + v1 + v2 + v3;
        float pq = v0 * v0 + v1 * v1 + v2 * v2 + v3 * v3;
        int tl = tt * 16 + (l & 15);
        redS[tl * 41 + w * 4 + kb] = ps;
        redQ[tl * 41 + w * 4 + kb] = pq;
    }
    __syncthreads();

    if (tid < 64) {
        float s = 0.f, q = 0.f;
        #pragma unroll 8
        for (int j = 0; j < 40; ++j) {
            s += redS[tid * 41 + j];
            q += redQ[tid * 41 + j];
        }
        float mean = s * (1.f / NF);
        float var = q * (1.f / NF) - mean * mean;
        lnM[tid] = mean;
        lnI[tid] = 1.f / sqrtf(var + 1e-5f);
    }
    __syncthreads();

    float* Qb = Qn + (size_t)bc * NF * NTP;
    #pragma unroll
    for (int tt = 0; tt < 4; ++tt) {
        f32x4 a = (tt == 0) ? acc0 : (tt == 1) ? acc1 : (tt == 2) ? acc2 : acc3;
        int tl = tt * 16 + (l & 15);
        int t = t0 + tl;
        float mean = lnM[tl], inv = lnI[tl];
        if (t < NT) {
            #pragma unroll
            for (int r = 0; r < 4; ++r) {
                int fo = 16 * w + kb * 4 + r;
                float v = a[r] + qlbv[r];
                float vn = ((v - mean) * inv * qngv[r] + qnbv[r]) * sgqv[r];
                Qb[(size_t)fo * NTP + 3 + t] = vn;
            }
        }
    }

    // padded rows u = 0..2 (input = zeros -> LN(ql_b))
    if (t0 == 0 && tid < 3 * NF) {
        int ttp = tid / NF;
        int f = tid - ttp * NF;
        float s2 = 0.f, q2 = 0.f;
        for (int j = 0; j < NF; ++j) {
            float vj = qlb[j];
            s2 += vj;
            q2 = fmaf(vj, vj, q2);
        }
        float mn = s2 * (1.f / NF);
        float vr = q2 * (1.f / NF) - mn * mn;
        float iv = 1.f / sqrtf(vr + 1e-5f);
        float sq = 1.f / (1.f + expf(-qvec[f]));
        Qb[(size_t)f * NTP + ttp] = ((qlb[f] - mn) * iv * qng[f] + qnb[f]) * sq;
    }
}

// ---------------------------------------------------------------------------
// k3 v3: one SITE PER LANE, f serial. Block = 8 waves over one 64-t tile;
// wave w handles f-slice [20w, 20w+20). No shuffles, no input staging:
// mix/Qn reads are coalesced (consecutive lanes = consecutive t).
// Partials combine via conflict-free stride-20 LDS buffer; wave 0 does
// softmax + coalesced W write.
// ---------------------------------------------------------------------------
__global__ __launch_bounds__(512) void k3_attn_v3(const float* __restrict__ mix,
                                                  const float* __restrict__ Qn,
                                                  const float* __restrict__ kcw,
                                                  const float* __restrict__ kcb,
                                                  const float* __restrict__ klw,
                                                  const float* __restrict__ klb,
                                                  const float* __restrict__ kng,
                                                  const float* __restrict__ knb,
                                                  const float* __restrict__ kvec,
                                                  float* __restrict__ W) {
    __shared__ float buf[8 * 64 * 20];    // [wave][lane][16 used of 20]

    const int bc = blockIdx.x;        // 0..15
    const int t0 = blockIdx.y * 64;   // 0..960
    const int b = bc >> 1, c = bc & 1;
    const int tid = threadIdx.x;
    const int w = __builtin_amdgcn_readfirstlane(tid >> 6);  // 0..7
    const int lane = tid & 63;
    const int t = t0 + lane;
    const bool valid = t < NT;

    float kw0[4], kw1[4], kb[4], klwm[16], klbv[4], kngv[4], knbv[4], sigk[4];
    #pragma unroll
    for (int j = 0; j < 4; ++j) {
        kw0[j] = kcw[(4 * c + j) * 2 + 0];
        kw1[j] = kcw[(4 * c + j) * 2 + 1];
        kb[j]  = kcb[4 * c + j];
        klbv[j] = klb[j];
        kngv[j] = kng[j];
        knbv[j] = knb[j];
        sigk[j] = 0.5f / (1.f + expf(-kvec[j]));   // sigmoid(k_vec)/sqrt(k)
    }
    #pragma unroll
    for (int x = 0; x < 16; ++x) klwm[x] = klw[x];

    float s[16];
    #pragma unroll
    for (int x = 0; x < 16; ++x) s[x] = 0.f;

    const float* mix0 = mix + (size_t)(b * 2) * NF * NT;
    const float* mix1 = mix0 + (size_t)NF * NT;
    const float* Qb = Qn + (size_t)bc * NF * NTP;
    const int f0 = w * 20;

    if (valid) {
        #pragma unroll 4
        for (int ff = 0; ff < 20; ++ff) {
            int f = f0 + ff;
            float m0 = mix0[(size_t)f * NT + t];
            float m1 = mix1[(size_t)f * NT + t];
            float kraw[4], klin[4];
            #pragma unroll
            for (int j = 0; j < 4; ++j)
                kraw[j] = fmaf(kw0[j], m0, fmaf(kw1[j], m1, kb[j]));
            #pragma unroll
            for (int jo = 0; jo < 4; ++jo) {
                float a = klbv[jo];
                #pragma unroll
                for (int ji = 0; ji < 4; ++ji) a = fmaf(klwm[jo * 4 + ji], kraw[ji], a);
                klin[jo] = a;
            }
            float mn = 0.25f * (klin[0] + klin[1] + klin[2] + klin[3]);
            float d0 = klin[0] - mn, d1 = klin[1] - mn, d2 = klin[2] - mn, d3 = klin[3] - mn;
            float var = 0.25f * (d0 * d0 + d1 * d1 + d2 * d2 + d3 * d3);
            float inv = 1.f / sqrtf(var + 1e-5f);
            float kn[4];
            kn[0] = (d0 * inv * kngv[0] + knbv[0]) * sigk[0];
            kn[1] = (d1 * inv * kngv[1] + knbv[1]) * sigk[1];
            kn[2] = (d2 * inv * kngv[2] + knbv[2]) * sigk[2];
            kn[3] = (d3 * inv * kngv[3] + knbv[3]) * sigk[3];

            const float* qp = Qb + (size_t)f * NTP + t;
            float q0 = qp[0], q1 = qp[1], q2 = qp[2], q3 = qp[3];
            #pragma unroll
            for (int j = 0; j < 4; ++j) {
                s[0 * 4 + j] = fmaf(q0, kn[j], s[0 * 4 + j]);
                s[1 * 4 + j] = fmaf(q1, kn[j], s[1 * 4 + j]);
                s[2 * 4 + j] = fmaf(q2, kn[j], s[2 * 4 + j]);
                s[3 * 4 + j] = fmaf(q3, kn[j], s[3 * 4 + j]);
            }
        }
    }

    // park partials: buf[(w*64+lane)*20 + x], stride 20 floats (80B, b128-aligned,
    // bank-group (5*lane)%8 -> conflict-free)
    {
        float* dst = &buf[(w * 64 + lane) * 20];
        #pragma unroll
        for (int q4 = 0; q4 < 4; ++q4) {
            float4 v = {s[q4 * 4 + 0], s[q4 * 4 + 1], s[q4 * 4 + 2], s[q4 * 4 + 3]};
            *(float4*)(dst + q4 * 4) = v;
        }
    }
    __syncthreads();

    if (tid < 64 && valid) {
        float r[16];
        #pragma unroll
        for (int q4 = 0; q4 < 4; ++q4) {
            float4 a = *(const float4*)&buf[(0 * 64 + lane) * 20 + q4 * 4];
            #pragma unroll
            for (int ww = 1; ww < 8; ++ww) {
                float4 p = *(const float4*)&buf[(ww * 64 + lane) * 20 + q4 * 4];
                a.x += p.x; a.y += p.y; a.z += p.z; a.w += p.w;
            }
            r[q4 * 4 + 0] = a.x; r[q4 * 4 + 1] = a.y; r[q4 * 4 + 2] = a.z; r[q4 * 4 + 3] = a.w;
        }
        float* wp = W + ((size_t)bc * NT + t) * 16;
        #pragma unroll
        for (int i = 0; i < 4; ++i) {
            float a = r[i * 4 + 0], b2 = r[i * 4 + 1], c2 = r[i * 4 + 2], d2 = r[i * 4 + 3];
            float mx = fmaxf(fmaxf(a, b2), fmaxf(c2, d2));
            float e0 = expf(a - mx), e1 = expf(b2 - mx), e2 = expf(c2 - mx), e3 = expf(d2 - mx);
            float inv = 1.f / (e0 + e1 + e2 + e3);
            float4 v = {e0 * inv, e1 * inv, e2 * inv, e3 * inv};
            *(float4*)(wp + i * 4) = v;
        }
    }
}

// ---------------------------------------------------------------------------
// complex 4x4 solve, partial pivoting (cabs1), fully unrolled
// ---------------------------------------------------------------------------
__device__ __forceinline__ void csolve4(float Ar[16], float Ai[16],
                                        float br[4], float bi[4],
                                        float wr[4], float wi[4]) {
    #pragma unroll
    for (int col = 0; col < 4; ++col) {
        #pragma unroll
        for (int r = col + 1; r < 4; ++r) {
            float cp = fabsf(Ar[col * 4 + col]) + fabsf(Ai[col * 4 + col]);
            float cr = fabsf(Ar[r * 4 + col]) + fabsf(Ai[r * 4 + col]);
            bool sw = cr > cp;
            #pragma unroll
            for (int m = col; m < 4; ++m) {
                float a0 = Ar[col * 4 + m], a1 = Ar[r * 4 + m];
                Ar[col * 4 + m] = sw ? a1 : a0;
                Ar[r * 4 + m]   = sw ? a0 : a1;
                float c0 = Ai[col * 4 + m], c1 = Ai[r * 4 + m];
                Ai[col * 4 + m] = sw ? c1 : c0;
                Ai[r * 4 + m]   = sw ? c0 : c1;
            }
            float b0 = br[col], b1 = br[r];
            br[col] = sw ? b1 : b0; br[r] = sw ? b0 : b1;
            float d0 = bi[col], d1 = bi[r];
            bi[col] = sw ? d1 : d0; bi[r] = sw ? d0 : d1;
        }
        float pr = Ar[col * 4 + col], pi = Ai[col * 4 + col];
        float den = 1.f / (pr * pr + pi * pi);
        #pragma unroll
        for (int r = col + 1; r < 4; ++r) {
            float nr = Ar[r * 4 + col], ni = Ai[r * 4 + col];
            float fr = (nr * pr + ni * pi) * den;
            float fi = (ni * pr - nr * pi) * den;
            #pragma unroll
            for (int m = col + 1; m < 4; ++m) {
                float tr = Ar[col * 4 + m], ti = Ai[col * 4 + m];
                Ar[r * 4 + m] -= fr * tr - fi * ti;
                Ai[r * 4 + m] -= fr * ti + fi * tr;
            }
            float tr = br[col], ti = bi[col];
            br[r] -= fr * tr - fi * ti;
            bi[r] -= fr * ti + fi * tr;
        }
    }
    #pragma unroll
    for (int col = 3; col >= 0; --col) {
        float sr = br[col], si = bi[col];
        #pragma unroll
        for (int m = col + 1; m < 4; ++m) {
            float tr = Ar[col * 4 + m], ti = Ai[col * 4 + m];
            sr -= tr * wr[m] - ti * wi[m];
            si -= tr * wi[m] + ti * wr[m];
        }
        float pr = Ar[col * 4 + col], pi = Ai[col * 4 + col];
        float den = 1.f / (pr * pr + pi * pi);
        wr[col] = (sr * pr + si * pi) * den;
        wi[col] = (si * pr - sr * pi) * den;
    }
}

// ---------------------------------------------------------------------------
// k4: per (b,f,t): build rank-1 value/out, assemble A,rhs, solve, Wiener sum
// ---------------------------------------------------------------------------
__global__ __launch_bounds__(256) void k4_final(const float* __restrict__ far,
                                                const float* __restrict__ mix,
                                                const float* __restrict__ Wt,
                                                const float* __restrict__ vvec,
                                                float* __restrict__ out) {
    const int t = blockIdx.x * 256 + threadIdx.x;
    const int f = blockIdx.y;
    const int b = blockIdx.z;
    if (t >= NT) return;

    const float* fr  = far + (size_t)(b * 2 + 0) * NF * NT + (size_t)f * NT;
    const float* fim = far + (size_t)(b * 2 + 1) * NF * NT + (size_t)f * NT;
    float ur[4], ui[4];
    #pragma unroll
    for (int d = 0; d < 4; ++d) {
        int tp = t - 3 + d;
        bool ok = tp >= 0;
        ur[d] = ok ? fr[tp] : 0.f;
        ui[d] = ok ? fim[tp] : 0.f;
    }
    float m0 = mix[(size_t)(b * 2 + 0) * NF * NT + (size_t)f * NT + t];
    float m1 = mix[(size_t)(b * 2 + 1) * NF * NT + (size_t)f * NT + t];

    float sv[4];
    #pragma unroll
    for (int i = 0; i < 4; ++i) sv[i] = 1.f / (1.f + expf(-vvec[i]));

    const float* w0p = Wt + ((size_t)(b * 2 + 0) * NT + t) * 16;
    const float* w1p = Wt + ((size_t)(b * 2 + 1) * NT + t) * 16;

    float g0[4], g1[4];
    #pragma unroll
    for (int j = 0; j < 4; ++j) { g0[j] = 0.f; g1[j] = 0.f; }
    #pragma unroll
    for (int i = 0; i < 4; ++i) {
        float a0 = ur[i] * sv[i];
        float a1 = -ui[i] * sv[i];
        #pragma unroll
        for (int j = 0; j < 4; ++j) {
            g0[j] = fmaf(a0, w0p[i * 4 + j], g0[j]);
            g1[j] = fmaf(a1, w1p[i * 4 + j], g1[j]);
        }
    }

    float Ar[16], Ai[16], br[4], bi[4], wr[4], wi[4];
    #pragma unroll
    for (int j = 0; j < 4; ++j) {
        #pragma unroll
        for (int m = 0; m < 4; ++m) {
            float e = (j == m) ? (1.0f + 1e-8f) : 1e-8f;
            Ar[j * 4 + m] = fmaf(ur[m], g0[j], e);
            Ai[j * 4 + m] = fmaf(-ui[m], g1[j], e);
        }
        br[j] = m0 * g0[j];
        bi[j] = m1 * g1[j];
    }

    csolve4(Ar, Ai, br, bi, wr, wi);

    float resr = 0.f, resi = 0.f;
    #pragma unroll
    for (int d = 0; d < 4; ++d) {
        resr += ur[d] * wr[d] - ui[d] * wi[d];
        resi += ur[d] * wi[d] + ui[d] * wr[d];
    }
    out[(size_t)(b * 2 + 0) * NF * NT + (size_t)f * NT + t] = resr;
    out[(size_t)(b * 2 + 1) * NF * NT + (size_t)f * NT + t] = resi;
}

// ---------------------------------------------------------------------------
extern "C" void kernel_launch(void* const* d_in, const int* in_sizes, int n_in,
                              void* d_out, int out_size, void* d_ws, size_t ws_size,
                              hipStream_t stream) {
    const float* far  = (const float*)d_in[0];
    const float* mix  = (const float*)d_in[1];
    const float* kcw  = (const float*)d_in[2];
    const float* kcb  = (const float*)d_in[3];
    const float* qlw  = (const float*)d_in[4];
    const float* qlb  = (const float*)d_in[5];
    const float* qng  = (const float*)d_in[6];
    const float* qnb  = (const float*)d_in[7];
    const float* klw  = (const float*)d_in[8];
    const float* klb  = (const float*)d_in[9];
    const float* kng  = (const float*)d_in[10];
    const float* knb  = (const float*)d_in[11];
    const float* qvec = (const float*)d_in[12];
    const float* kvec = (const float*)d_in[13];
    const float* vvec = (const float*)d_in[14];

    float* Qn = (float*)d_ws;                       // 16*160*NTP
    float* W  = Qn + (size_t)NBC * NF * NTP;        // 16*1000*16
    float* out = (float*)d_out;

    k1_mfma_ln<<<dim3(NBC, 16), 640, 0, stream>>>(far, qlw, qlb, qng, qnb, qvec, Qn);
    k3_attn_v3<<<dim3(NBC, 16), 512, 0, stream>>>(mix, Qn, kcw, kcb, klw, klb,
                                                  kng, knb, kvec, W);
    k4_final<<<dim3(4, NF, 8), 256, 0, stream>>>(far, mix, W, vvec, out);
}

// Round 7
// 56.997 us; speedup vs baseline: 1.5980x; 1.1188x over previous
//
#include <hip/hip_runtime.h>
#include <math.h>

#define NBC   16          // b*2
#define NF    160
#define NT    1000
#define NTP   1040        // Qn t-stride (padded; u index = t+3, u in [0,1003))

typedef __attribute__((ext_vector_type(8))) short short8;
typedef __attribute__((ext_vector_type(4))) float f32x4;

static __device__ __forceinline__ short f2bf(float x) {
    unsigned u = __builtin_bit_cast(unsigned, x);
    unsigned r = (u + 0x7fffu + ((u >> 16) & 1u)) >> 16;
    return (short)r;
}
static __device__ __forceinline__ float bf2f(short s) {
    unsigned u = ((unsigned)(unsigned short)s) << 16;
    return __builtin_bit_cast(float, u);
}

// ---------------------------------------------------------------------------
// k1 (MFMA): P = ql_w @ (sgn*far) via split-bf16 mfma_f32_16x16x32_bf16,
// then LayerNorm over fo + *sigmoid(q_vec); writes Qn[bc][f][u], u = t+3.
// ---------------------------------------------------------------------------
__global__ __launch_bounds__(640) void k1_mfma_ln(const float* __restrict__ far,
                                                  const float* __restrict__ qlw,
                                                  const float* __restrict__ qlb,
                                                  const float* __restrict__ qng,
                                                  const float* __restrict__ qnb,
                                                  const float* __restrict__ qvec,
                                                  float* __restrict__ Qn) {
    __shared__ float Xs[NF * 66];          // fp32 stage, stride 66
    __shared__ short Bhi[5 * 4 * 64 * 8];  // B fragments hi (bf16)
    __shared__ short Blo[5 * 4 * 64 * 8];  // B fragments lo
    __shared__ float redS[64 * 41];
    __shared__ float redQ[64 * 41];
    __shared__ float lnM[64], lnI[64];

    const int bc = blockIdx.x;
    const int t0 = blockIdx.y * 64;
    const int tid = threadIdx.x;
    const float sgn = (bc & 1) ? -1.f : 1.f;
    const float* Xb = far + (size_t)bc * NF * NT;

    const int w = __builtin_amdgcn_readfirstlane(tid >> 6);  // wave 0..9
    const int l = tid & 63;
    const int row = l & 15;        // A row / D col
    const int kb = l >> 4;         // k-block 0..3

    // ---- A fragments (weights) -> registers, hi/lo bf16 ----
    short8 Ahi[5], Alo[5];
    #pragma unroll
    for (int fc = 0; fc < 5; ++fc) {
        const float* ap = qlw + (size_t)(16 * w + row) * NF + fc * 32 + kb * 8;
        float4 x0 = *(const float4*)(ap + 0);
        float4 x1 = *(const float4*)(ap + 4);
        float xv[8] = {x0.x, x0.y, x0.z, x0.w, x1.x, x1.y, x1.z, x1.w};
        short8 h, lo;
        #pragma unroll
        for (int j = 0; j < 8; ++j) {
            short hj = f2bf(xv[j]);
            h[j] = hj;
            lo[j] = f2bf(xv[j] - bf2f(hj));
        }
        Ahi[fc] = h; Alo[fc] = lo;
    }

    // ---- stage X fp32 (160 x 64), sign applied ----
    #pragma unroll
    for (int i = 0; i < 16; ++i) {
        int o = tid + i * 640;
        int fi = o >> 6, tl0 = o & 63;
        int t = t0 + tl0;
        Xs[fi * 66 + tl0] = (t < NT) ? Xb[fi * NT + t] * sgn : 0.f;
    }
    __syncthreads();

    // ---- convert to B fragments (hi/lo), fragment-layout LDS ----
    #pragma unroll
    for (int e = 0; e < 2; ++e) {
        int slot = tid * 2 + e;            // (fc*4+tt)*64 + lane
        int sl = slot & 63;
        int g = slot >> 6;                 // fc*4+tt
        int fi0 = (g >> 2) * 32 + ((sl >> 4) << 3);
        int tloc = (g & 3) * 16 + (sl & 15);
        short8 h, lo;
        #pragma unroll
        for (int j = 0; j < 8; ++j) {
            float x = Xs[(fi0 + j) * 66 + tloc];
            short hj = f2bf(x);
            h[j] = hj;
            lo[j] = f2bf(x - bf2f(hj));
        }
        *(short8*)&Bhi[slot * 8] = h;
        *(short8*)&Blo[slot * 8] = lo;
    }
    __syncthreads();

    // ---- MFMA main: acc[tt] = W·X for this wave's 16 fo rows ----
    f32x4 acc0 = {0.f, 0.f, 0.f, 0.f}, acc1 = acc0, acc2 = acc0, acc3 = acc0;
    #pragma unroll
    for (int fc = 0; fc < 5; ++fc) {
        #pragma unroll
        for (int tt = 0; tt < 4; ++tt) {
            short8 bh = *(const short8*)&Bhi[((fc * 4 + tt) * 64 + l) * 8];
            short8 bl = *(const short8*)&Blo[((fc * 4 + tt) * 64 + l) * 8];
            f32x4 a = (tt == 0) ? acc0 : (tt == 1) ? acc1 : (tt == 2) ? acc2 : acc3;
            a = __builtin_amdgcn_mfma_f32_16x16x32_bf16(Ahi[fc], bh, a, 0, 0, 0);
            a = __builtin_amdgcn_mfma_f32_16x16x32_bf16(Ahi[fc], bl, a, 0, 0, 0);
            a = __builtin_amdgcn_mfma_f32_16x16x32_bf16(Alo[fc], bh, a, 0, 0, 0);
            if (tt == 0) acc0 = a; else if (tt == 1) acc1 = a; else if (tt == 2) acc2 = a; else acc3 = a;
        }
    }

    // D layout: col(t) = l&15, row(fo) = kb*4 + reg
    float qlbv[4], qngv[4], qnbv[4], sgqv[4];
    #pragma unroll
    for (int r = 0; r < 4; ++r) {
        int fo = 16 * w + kb * 4 + r;
        qlbv[r] = qlb[fo];
        qngv[r] = qng[fo];
        qnbv[r] = qnb[fo];
        sgqv[r] = 1.f / (1.f + expf(-qvec[fo]));
    }

    #pragma unroll
    for (int tt = 0; tt < 4; ++tt) {
        f32x4 a = (tt == 0) ? acc0 : (tt == 1) ? acc1 : (tt == 2) ? acc2 : acc3;
        float v0 = a[0] + qlbv[0], v1 = a[1] + qlbv[1];
        float v2 = a[2] + qlbv[2], v3 = a[3] + qlbv[3];
        float ps = v0 + v1 + v2 + v3;
        float pq = v0 * v0 + v1 * v1 + v2 * v2 + v3 * v3;
        int tl = tt * 16 + (l & 15);
        redS[tl * 41 + w * 4 + kb] = ps;
        redQ[tl * 41 + w * 4 + kb] = pq;
    }
    __syncthreads();

    if (tid < 64) {
        float s = 0.f, q = 0.f;
        #pragma unroll 8
        for (int j = 0; j < 40; ++j) {
            s += redS[tid * 41 + j];
            q += redQ[tid * 41 + j];
        }
        float mean = s * (1.f / NF);
        float var = q * (1.f / NF) - mean * mean;
        lnM[tid] = mean;
        lnI[tid] = 1.f / sqrtf(var + 1e-5f);
    }
    __syncthreads();

    float* Qb = Qn + (size_t)bc * NF * NTP;
    #pragma unroll
    for (int tt = 0; tt < 4; ++tt) {
        f32x4 a = (tt == 0) ? acc0 : (tt == 1) ? acc1 : (tt == 2) ? acc2 : acc3;
        int tl = tt * 16 + (l & 15);
        int t = t0 + tl;
        float mean = lnM[tl], inv = lnI[tl];
        if (t < NT) {
            #pragma unroll
            for (int r = 0; r < 4; ++r) {
                int fo = 16 * w + kb * 4 + r;
                float v = a[r] + qlbv[r];
                float vn = ((v - mean) * inv * qngv[r] + qnbv[r]) * sgqv[r];
                Qb[(size_t)fo * NTP + 3 + t] = vn;
            }
        }
    }

    // padded rows u = 0..2 (input = zeros -> LN(ql_b))
    if (t0 == 0 && tid < 3 * NF) {
        int ttp = tid / NF;
        int f = tid - ttp * NF;
        float s2 = 0.f, q2 = 0.f;
        for (int j = 0; j < NF; ++j) {
            float vj = qlb[j];
            s2 += vj;
            q2 = fmaf(vj, vj, q2);
        }
        float mn = s2 * (1.f / NF);
        float vr = q2 * (1.f / NF) - mn * mn;
        float iv = 1.f / sqrtf(vr + 1e-5f);
        float sq = 1.f / (1.f + expf(-qvec[f]));
        Qb[(size_t)f * NTP + ttp] = ((qlb[f] - mn) * iv * qng[f] + qnb[f]) * sq;
    }
}

// ---------------------------------------------------------------------------
// k3 v4: one SITE PER LANE, 16 waves (4/SIMD) splitting f 16x10.
// No shuffles, no input staging (coalesced global reads). Cross-wave combine
// via stride-17 LDS; 4 waves do the quadrant-local softmax + float4 W write.
// ---------------------------------------------------------------------------
__global__ __launch_bounds__(1024) void k3_attn_v4(const float* __restrict__ mix,
                                                   const float* __restrict__ Qn,
                                                   const float* __restrict__ kcw,
                                                   const float* __restrict__ kcb,
                                                   const float* __restrict__ klw,
                                                   const float* __restrict__ klb,
                                                   const float* __restrict__ kng,
                                                   const float* __restrict__ knb,
                                                   const float* __restrict__ kvec,
                                                   float* __restrict__ W) {
    __shared__ float buf[16 * 64 * 17];   // [wave][lane][16 used of 17] = 69.6 KB

    const int bc = blockIdx.x;        // 0..15
    const int t0 = blockIdx.y * 64;   // 0..960
    const int b = bc >> 1, c = bc & 1;
    const int tid = threadIdx.x;
    const int w = __builtin_amdgcn_readfirstlane(tid >> 6);  // 0..15
    const int lane = tid & 63;
    const int t = t0 + lane;
    const bool valid = t < NT;

    float kw0[4], kw1[4], kb[4], klwm[16], klbv[4], kngv[4], knbv[4], sigk[4];
    #pragma unroll
    for (int j = 0; j < 4; ++j) {
        kw0[j] = kcw[(4 * c + j) * 2 + 0];
        kw1[j] = kcw[(4 * c + j) * 2 + 1];
        kb[j]  = kcb[4 * c + j];
        klbv[j] = klb[j];
        kngv[j] = kng[j];
        knbv[j] = knb[j];
        sigk[j] = 0.5f / (1.f + expf(-kvec[j]));   // sigmoid(k_vec)/sqrt(k)
    }
    #pragma unroll
    for (int x = 0; x < 16; ++x) klwm[x] = klw[x];

    float s[16];
    #pragma unroll
    for (int x = 0; x < 16; ++x) s[x] = 0.f;

    const float* mix0 = mix + (size_t)(b * 2) * NF * NT;
    const float* mix1 = mix0 + (size_t)NF * NT;
    const float* Qb = Qn + (size_t)bc * NF * NTP;
    const int f0 = w * 10;

    if (valid) {
        #pragma unroll 5
        for (int ff = 0; ff < 10; ++ff) {
            int f = f0 + ff;
            float m0 = mix0[(size_t)f * NT + t];
            float m1 = mix1[(size_t)f * NT + t];
            float kraw[4], klin[4];
            #pragma unroll
            for (int j = 0; j < 4; ++j)
                kraw[j] = fmaf(kw0[j], m0, fmaf(kw1[j], m1, kb[j]));
            #pragma unroll
            for (int jo = 0; jo < 4; ++jo) {
                float a = klbv[jo];
                #pragma unroll
                for (int ji = 0; ji < 4; ++ji) a = fmaf(klwm[jo * 4 + ji], kraw[ji], a);
                klin[jo] = a;
            }
            float mn = 0.25f * (klin[0] + klin[1] + klin[2] + klin[3]);
            float d0 = klin[0] - mn, d1 = klin[1] - mn, d2 = klin[2] - mn, d3 = klin[3] - mn;
            float var = 0.25f * (d0 * d0 + d1 * d1 + d2 * d2 + d3 * d3);
            float inv = 1.f / sqrtf(var + 1e-5f);
            float kn[4];
            kn[0] = (d0 * inv * kngv[0] + knbv[0]) * sigk[0];
            kn[1] = (d1 * inv * kngv[1] + knbv[1]) * sigk[1];
            kn[2] = (d2 * inv * kngv[2] + knbv[2]) * sigk[2];
            kn[3] = (d3 * inv * kngv[3] + knbv[3]) * sigk[3];

            const float* qp = Qb + (size_t)f * NTP + t;
            float q0 = qp[0], q1 = qp[1], q2 = qp[2], q3 = qp[3];
            #pragma unroll
            for (int j = 0; j < 4; ++j) {
                s[0 * 4 + j] = fmaf(q0, kn[j], s[0 * 4 + j]);
                s[1 * 4 + j] = fmaf(q1, kn[j], s[1 * 4 + j]);
                s[2 * 4 + j] = fmaf(q2, kn[j], s[2 * 4 + j]);
                s[3 * 4 + j] = fmaf(q3, kn[j], s[3 * 4 + j]);
            }
        }
    }

    // park partials: buf[(w*64+lane)*17 + x]; stride 17 words (gcd(17,32)=1 ->
    // conflict-free across lanes)
    {
        float* dst = &buf[(w * 64 + lane) * 17];
        #pragma unroll
        for (int q4 = 0; q4 < 4; ++q4) {
            float4 v = {s[q4 * 4 + 0], s[q4 * 4 + 1], s[q4 * 4 + 2], s[q4 * 4 + 3]};
            *(float4*)(dst + q4 * 4) = v;
        }
    }
    __syncthreads();

    // reduce + quadrant-local softmax: 4 waves, thread = (quadrant, t-lane)
    if (tid < 256) {
        int q4 = tid >> 6;
        int ln = tid & 63;
        int tt = t0 + ln;
        if (tt < NT) {
            float4 a = *(const float4*)&buf[(0 * 64 + ln) * 17 + q4 * 4];
            #pragma unroll
            for (int ww = 1; ww < 16; ++ww) {
                float4 p = *(const float4*)&buf[(ww * 64 + ln) * 17 + q4 * 4];
                a.x += p.x; a.y += p.y; a.z += p.z; a.w += p.w;
            }
            float mx = fmaxf(fmaxf(a.x, a.y), fmaxf(a.z, a.w));
            float e0 = expf(a.x - mx), e1 = expf(a.y - mx);
            float e2 = expf(a.z - mx), e3 = expf(a.w - mx);
            float inv = 1.f / (e0 + e1 + e2 + e3);
            float4 v = {e0 * inv, e1 * inv, e2 * inv, e3 * inv};
            *(float4*)(W + ((size_t)bc * NT + tt) * 16 + q4 * 4) = v;
        }
    }
}

// ---------------------------------------------------------------------------
// complex 4x4 solve, partial pivoting (cabs1), fully unrolled
// ---------------------------------------------------------------------------
__device__ __forceinline__ void csolve4(float Ar[16], float Ai[16],
                                        float br[4], float bi[4],
                                        float wr[4], float wi[4]) {
    #pragma unroll
    for (int col = 0; col < 4; ++col) {
        #pragma unroll
        for (int r = col + 1; r < 4; ++r) {
            float cp = fabsf(Ar[col * 4 + col]) + fabsf(Ai[col * 4 + col]);
            float cr = fabsf(Ar[r * 4 + col]) + fabsf(Ai[r * 4 + col]);
            bool sw = cr > cp;
            #pragma unroll
            for (int m = col; m < 4; ++m) {
                float a0 = Ar[col * 4 + m], a1 = Ar[r * 4 + m];
                Ar[col * 4 + m] = sw ? a1 : a0;
                Ar[r * 4 + m]   = sw ? a0 : a1;
                float c0 = Ai[col * 4 + m], c1 = Ai[r * 4 + m];
                Ai[col * 4 + m] = sw ? c1 : c0;
                Ai[r * 4 + m]   = sw ? c0 : c1;
            }
            float b0 = br[col], b1 = br[r];
            br[col] = sw ? b1 : b0; br[r] = sw ? b0 : b1;
            float d0 = bi[col], d1 = bi[r];
            bi[col] = sw ? d1 : d0; bi[r] = sw ? d0 : d1;
        }
        float pr = Ar[col * 4 + col], pi = Ai[col * 4 + col];
        float den = 1.f / (pr * pr + pi * pi);
        #pragma unroll
        for (int r = col + 1; r < 4; ++r) {
            float nr = Ar[r * 4 + col], ni = Ai[r * 4 + col];
            float fr = (nr * pr + ni * pi) * den;
            float fi = (ni * pr - nr * pi) * den;
            #pragma unroll
            for (int m = col + 1; m < 4; ++m) {
                float tr = Ar[col * 4 + m], ti = Ai[col * 4 + m];
                Ar[r * 4 + m] -= fr * tr - fi * ti;
                Ai[r * 4 + m] -= fr * ti + fi * tr;
            }
            float tr = br[col], ti = bi[col];
            br[r] -= fr * tr - fi * ti;
            bi[r] -= fr * ti + fi * tr;
        }
    }
    #pragma unroll
    for (int col = 3; col >= 0; --col) {
        float sr = br[col], si = bi[col];
        #pragma unroll
        for (int m = col + 1; m < 4; ++m) {
            float tr = Ar[col * 4 + m], ti = Ai[col * 4 + m];
            sr -= tr * wr[m] - ti * wi[m];
            si -= tr * wi[m] + ti * wr[m];
        }
        float pr = Ar[col * 4 + col], pi = Ai[col * 4 + col];
        float den = 1.f / (pr * pr + pi * pi);
        wr[col] = (sr * pr + si * pi) * den;
        wi[col] = (si * pr - sr * pi) * den;
    }
}

// ---------------------------------------------------------------------------
// k4: per (b,f,t): build rank-1 value/out, assemble A,rhs, solve, Wiener sum
// ---------------------------------------------------------------------------
__global__ __launch_bounds__(256) void k4_final(const float* __restrict__ far,
                                                const float* __restrict__ mix,
                                                const float* __restrict__ Wt,
                                                const float* __restrict__ vvec,
                                                float* __restrict__ out) {
    const int t = blockIdx.x * 256 + threadIdx.x;
    const int f = blockIdx.y;
    const int b = blockIdx.z;
    if (t >= NT) return;

    const float* fr  = far + (size_t)(b * 2 + 0) * NF * NT + (size_t)f * NT;
    const float* fim = far + (size_t)(b * 2 + 1) * NF * NT + (size_t)f * NT;
    float ur[4], ui[4];
    #pragma unroll
    for (int d = 0; d < 4; ++d) {
        int tp = t - 3 + d;
        bool ok = tp >= 0;
        ur[d] = ok ? fr[tp] : 0.f;
        ui[d] = ok ? fim[tp] : 0.f;
    }
    float m0 = mix[(size_t)(b * 2 + 0) * NF * NT + (size_t)f * NT + t];
    float m1 = mix[(size_t)(b * 2 + 1) * NF * NT + (size_t)f * NT + t];

    float sv[4];
    #pragma unroll
    for (int i = 0; i < 4; ++i) sv[i] = 1.f / (1.f + expf(-vvec[i]));

    const float* w0p = Wt + ((size_t)(b * 2 + 0) * NT + t) * 16;
    const float* w1p = Wt + ((size_t)(b * 2 + 1) * NT + t) * 16;

    float g0[4], g1[4];
    #pragma unroll
    for (int j = 0; j < 4; ++j) { g0[j] = 0.f; g1[j] = 0.f; }
    #pragma unroll
    for (int i = 0; i < 4; ++i) {
        float a0 = ur[i] * sv[i];
        float a1 = -ui[i] * sv[i];
        #pragma unroll
        for (int j = 0; j < 4; ++j) {
            g0[j] = fmaf(a0, w0p[i * 4 + j], g0[j]);
            g1[j] = fmaf(a1, w1p[i * 4 + j], g1[j]);
        }
    }

    float Ar[16], Ai[16], br[4], bi[4], wr[4], wi[4];
    #pragma unroll
    for (int j = 0; j < 4; ++j) {
        #pragma unroll
        for (int m = 0; m < 4; ++m) {
            float e = (j == m) ? (1.0f + 1e-8f) : 1e-8f;
            Ar[j * 4 + m] = fmaf(ur[m], g0[j], e);
            Ai[j * 4 + m] = fmaf(-ui[m], g1[j], e);
        }
        br[j] = m0 * g0[j];
        bi[j] = m1 * g1[j];
    }

    csolve4(Ar, Ai, br, bi, wr, wi);

    float resr = 0.f, resi = 0.f;
    #pragma unroll
    for (int d = 0; d < 4; ++d) {
        resr += ur[d] * wr[d] - ui[d] * wi[d];
        resi += ur[d] * wi[d] + ui[d] * wr[d];
    }
    out[(size_t)(b * 2 + 0) * NF * NT + (size_t)f * NT + t] = resr;
    out[(size_t)(b * 2 + 1) * NF * NT + (size_t)f * NT + t] = resi;
}

// ---------------------------------------------------------------------------
extern "C" void kernel_launch(void* const* d_in, const int* in_sizes, int n_in,
                              void* d_out, int out_size, void* d_ws, size_t ws_size,
                              hipStream_t stream) {
    const float* far  = (const float*)d_in[0];
    const float* mix  = (const float*)d_in[1];
    const float* kcw  = (const float*)d_in[2];
    const float* kcb  = (const float*)d_in[3];
    const float* qlw  = (const float*)d_in[4];
    const float* qlb  = (const float*)d_in[5];
    const float* qng  = (const float*)d_in[6];
    const float* qnb  = (const float*)d_in[7];
    const float* klw  = (const float*)d_in[8];
    const float* klb  = (const float*)d_in[9];
    const float* kng  = (const float*)d_in[10];
    const float* knb  = (const float*)d_in[11];
    const float* qvec = (const float*)d_in[12];
    const float* kvec = (const float*)d_in[13];
    const float* vvec = (const float*)d_in[14];

    float* Qn = (float*)d_ws;                       // 16*160*NTP
    float* W  = Qn + (size_t)NBC * NF * NTP;        // 16*1000*16
    float* out = (float*)d_out;

    k1_mfma_ln<<<dim3(NBC, 16), 640, 0, stream>>>(far, qlw, qlb, qng, qnb, qvec, Qn);
    k3_attn_v4<<<dim3(NBC, 16), 1024, 0, stream>>>(mix, Qn, kcw, kcb, klw, klb,
                                                   kng, knb, kvec, W);
    k4_final<<<dim3(4, NF, 8), 256, 0, stream>>>(far, mix, W, vvec, out);
}

// Round 8
// 56.489 us; speedup vs baseline: 1.6124x; 1.0090x over previous
//
#include <hip/hip_runtime.h>
#include <math.h>

#define NBC   16          // b*2
#define NF    160
#define NT    1000
#define NTP   1040        // Qn t-stride (padded; u index = t+3, u in [0,1003))

typedef __attribute__((ext_vector_type(8))) short short8;
typedef __attribute__((ext_vector_type(4))) float f32x4;

static __device__ __forceinline__ short f2bf(float x) {
    unsigned u = __builtin_bit_cast(unsigned, x);
    unsigned r = (u + 0x7fffu + ((u >> 16) & 1u)) >> 16;
    return (short)r;
}
static __device__ __forceinline__ float bf2f(short s) {
    unsigned u = ((unsigned)(unsigned short)s) << 16;
    return __builtin_bit_cast(float, u);
}

// ---------------------------------------------------------------------------
// k1 (MFMA, 32-t tile): P = ql_w @ (sgn*far) via split-bf16 mfma 16x16x32,
// then LayerNorm over fo + *sigmoid(q_vec); writes Qn[bc][f][u], u = t+3.
// LDS ~52.6 KB -> 2 blocks/CU (vs 1 before): cross-block phase overlap hides
// the serial stage/convert/MFMA/LN chain. Grid (16, 32), 640 thr = 10 waves.
// ---------------------------------------------------------------------------
__global__ __launch_bounds__(640) void k1_mfma_ln(const float* __restrict__ far,
                                                  const float* __restrict__ qlw,
                                                  const float* __restrict__ qlb,
                                                  const float* __restrict__ qng,
                                                  const float* __restrict__ qnb,
                                                  const float* __restrict__ qvec,
                                                  float* __restrict__ Qn) {
    __shared__ float Xs[NF * 33];          // fp32 stage, stride 33 (21.1 KB)
    __shared__ short Bhi[10 * 64 * 8];     // B fragments hi (10.2 KB)
    __shared__ short Blo[10 * 64 * 8];     // B fragments lo (10.2 KB)
    __shared__ float redS[32 * 41];        // 5.25 KB
    __shared__ float redQ[32 * 41];        // 5.25 KB
    __shared__ float lnM[32], lnI[32];

    const int bc = blockIdx.x;
    const int t0 = blockIdx.y * 32;        // 0..992
    const int tid = threadIdx.x;
    const float sgn = (bc & 1) ? -1.f : 1.f;
    const float* Xb = far + (size_t)bc * NF * NT;

    const int w = __builtin_amdgcn_readfirstlane(tid >> 6);  // wave 0..9
    const int l = tid & 63;
    const int row = l & 15;        // A row / D col
    const int kb = l >> 4;         // k-block 0..3

    // ---- A fragments (weights) -> registers, hi/lo bf16 ----
    short8 Ahi[5], Alo[5];
    #pragma unroll
    for (int fc = 0; fc < 5; ++fc) {
        const float* ap = qlw + (size_t)(16 * w + row) * NF + fc * 32 + kb * 8;
        float4 x0 = *(const float4*)(ap + 0);
        float4 x1 = *(const float4*)(ap + 4);
        float xv[8] = {x0.x, x0.y, x0.z, x0.w, x1.x, x1.y, x1.z, x1.w};
        short8 h, lo;
        #pragma unroll
        for (int j = 0; j < 8; ++j) {
            short hj = f2bf(xv[j]);
            h[j] = hj;
            lo[j] = f2bf(xv[j] - bf2f(hj));
        }
        Ahi[fc] = h; Alo[fc] = lo;
    }

    // ---- stage X fp32 (160 f x 32 t), sign applied: 8 loads/thread ----
    #pragma unroll
    for (int i = 0; i < 8; ++i) {
        int o = tid + i * 640;
        int fi = o >> 5, tl0 = o & 31;
        int t = t0 + tl0;
        Xs[fi * 33 + tl0] = (t < NT) ? Xb[fi * NT + t] * sgn : 0.f;
    }
    __syncthreads();

    // ---- convert to B fragments (hi/lo): exactly 1 slot per thread ----
    {
        int sl = tid & 63;
        int g = tid >> 6;                  // fc*2 + tt, 0..9
        int fi0 = (g >> 1) * 32 + ((sl >> 4) << 3);
        int tloc = (g & 1) * 16 + (sl & 15);
        short8 h, lo;
        #pragma unroll
        for (int j = 0; j < 8; ++j) {
            float x = Xs[(fi0 + j) * 33 + tloc];
            short hj = f2bf(x);
            h[j] = hj;
            lo[j] = f2bf(x - bf2f(hj));
        }
        *(short8*)&Bhi[tid * 8] = h;
        *(short8*)&Blo[tid * 8] = lo;
    }
    __syncthreads();

    // ---- MFMA main: acc[tt] = W·X for this wave's 16 fo rows ----
    f32x4 acc0 = {0.f, 0.f, 0.f, 0.f}, acc1 = acc0;
    #pragma unroll
    for (int fc = 0; fc < 5; ++fc) {
        {
            short8 bh = *(const short8*)&Bhi[((fc * 2 + 0) * 64 + l) * 8];
            short8 bl = *(const short8*)&Blo[((fc * 2 + 0) * 64 + l) * 8];
            acc0 = __builtin_amdgcn_mfma_f32_16x16x32_bf16(Ahi[fc], bh, acc0, 0, 0, 0);
            acc0 = __builtin_amdgcn_mfma_f32_16x16x32_bf16(Ahi[fc], bl, acc0, 0, 0, 0);
            acc0 = __builtin_amdgcn_mfma_f32_16x16x32_bf16(Alo[fc], bh, acc0, 0, 0, 0);
        }
        {
            short8 bh = *(const short8*)&Bhi[((fc * 2 + 1) * 64 + l) * 8];
            short8 bl = *(const short8*)&Blo[((fc * 2 + 1) * 64 + l) * 8];
            acc1 = __builtin_amdgcn_mfma_f32_16x16x32_bf16(Ahi[fc], bh, acc1, 0, 0, 0);
            acc1 = __builtin_amdgcn_mfma_f32_16x16x32_bf16(Ahi[fc], bl, acc1, 0, 0, 0);
            acc1 = __builtin_amdgcn_mfma_f32_16x16x32_bf16(Alo[fc], bh, acc1, 0, 0, 0);
        }
    }

    // D layout: col(t-local) = l&15, row(fo) = kb*4 + reg
    float qlbv[4], qngv[4], qnbv[4], sgqv[4];
    #pragma unroll
    for (int r = 0; r < 4; ++r) {
        int fo = 16 * w + kb * 4 + r;
        qlbv[r] = qlb[fo];
        qngv[r] = qng[fo];
        qnbv[r] = qnb[fo];
        sgqv[r] = 1.f / (1.f + expf(-qvec[fo]));
    }

    #pragma unroll
    for (int tt = 0; tt < 2; ++tt) {
        f32x4 a = tt ? acc1 : acc0;
        float v0 = a[0] + qlbv[0], v1 = a[1] + qlbv[1];
        float v2 = a[2] + qlbv[2], v3 = a[3] + qlbv[3];
        float ps = v0 + v1 + v2 + v3;
        float pq = v0 * v0 + v1 * v1 + v2 * v2 + v3 * v3;
        int tl = tt * 16 + row;
        redS[tl * 41 + w * 4 + kb] = ps;
        redQ[tl * 41 + w * 4 + kb] = pq;
    }
    __syncthreads();

    if (tid < 32) {
        float s = 0.f, q = 0.f;
        #pragma unroll 8
        for (int j = 0; j < 40; ++j) {
            s += redS[tid * 41 + j];
            q += redQ[tid * 41 + j];
        }
        float mean = s * (1.f / NF);
        float var = q * (1.f / NF) - mean * mean;
        lnM[tid] = mean;
        lnI[tid] = 1.f / sqrtf(var + 1e-5f);
    }
    __syncthreads();

    float* Qb = Qn + (size_t)bc * NF * NTP;
    #pragma unroll
    for (int tt = 0; tt < 2; ++tt) {
        f32x4 a = tt ? acc1 : acc0;
        int tl = tt * 16 + row;
        int t = t0 + tl;
        float mean = lnM[tl], inv = lnI[tl];
        if (t < NT) {
            #pragma unroll
            for (int r = 0; r < 4; ++r) {
                int fo = 16 * w + kb * 4 + r;
                float v = a[r] + qlbv[r];
                float vn = ((v - mean) * inv * qngv[r] + qnbv[r]) * sgqv[r];
                Qb[(size_t)fo * NTP + 3 + t] = vn;
            }
        }
    }

    // padded rows u = 0..2 (input = zeros -> LN(ql_b))
    if (t0 == 0 && tid < 3 * NF) {
        int ttp = tid / NF;
        int f = tid - ttp * NF;
        float s2 = 0.f, q2 = 0.f;
        for (int j = 0; j < NF; ++j) {
            float vj = qlb[j];
            s2 += vj;
            q2 = fmaf(vj, vj, q2);
        }
        float mn = s2 * (1.f / NF);
        float vr = q2 * (1.f / NF) - mn * mn;
        float iv = 1.f / sqrtf(vr + 1e-5f);
        float sq = 1.f / (1.f + expf(-qvec[f]));
        Qb[(size_t)f * NTP + ttp] = ((qlb[f] - mn) * iv * qng[f] + qnb[f]) * sq;
    }
}

// ---------------------------------------------------------------------------
// k3 v5: one SITE PER LANE, 16 waves (4/SIMD) splitting f 16x10.
// Full unroll -> all ~60 independent loads in flight (max MLP).
// ---------------------------------------------------------------------------
__global__ __launch_bounds__(1024) void k3_attn_v5(const float* __restrict__ mix,
                                                   const float* __restrict__ Qn,
                                                   const float* __restrict__ kcw,
                                                   const float* __restrict__ kcb,
                                                   const float* __restrict__ klw,
                                                   const float* __restrict__ klb,
                                                   const float* __restrict__ kng,
                                                   const float* __restrict__ knb,
                                                   const float* __restrict__ kvec,
                                                   float* __restrict__ W) {
    __shared__ float buf[16 * 64 * 17];   // [wave][lane][16 used of 17] = 69.6 KB

    const int bc = blockIdx.x;        // 0..15
    const int t0 = blockIdx.y * 64;   // 0..960
    const int b = bc >> 1, c = bc & 1;
    const int tid = threadIdx.x;
    const int w = __builtin_amdgcn_readfirstlane(tid >> 6);  // 0..15
    const int lane = tid & 63;
    const int t = t0 + lane;
    const bool valid = t < NT;

    float kw0[4], kw1[4], kb[4], klwm[16], klbv[4], kngv[4], knbv[4], sigk[4];
    #pragma unroll
    for (int j = 0; j < 4; ++j) {
        kw0[j] = kcw[(4 * c + j) * 2 + 0];
        kw1[j] = kcw[(4 * c + j) * 2 + 1];
        kb[j]  = kcb[4 * c + j];
        klbv[j] = klb[j];
        kngv[j] = kng[j];
        knbv[j] = knb[j];
        sigk[j] = 0.5f / (1.f + expf(-kvec[j]));   // sigmoid(k_vec)/sqrt(k)
    }
    #pragma unroll
    for (int x = 0; x < 16; ++x) klwm[x] = klw[x];

    float s[16];
    #pragma unroll
    for (int x = 0; x < 16; ++x) s[x] = 0.f;

    const float* mix0 = mix + (size_t)(b * 2) * NF * NT;
    const float* mix1 = mix0 + (size_t)NF * NT;
    const float* Qb = Qn + (size_t)bc * NF * NTP;
    const int f0 = w * 10;

    if (valid) {
        #pragma unroll
        for (int ff = 0; ff < 10; ++ff) {
            int f = f0 + ff;
            float m0 = mix0[(size_t)f * NT + t];
            float m1 = mix1[(size_t)f * NT + t];
            float kraw[4], klin[4];
            #pragma unroll
            for (int j = 0; j < 4; ++j)
                kraw[j] = fmaf(kw0[j], m0, fmaf(kw1[j], m1, kb[j]));
            #pragma unroll
            for (int jo = 0; jo < 4; ++jo) {
                float a = klbv[jo];
                #pragma unroll
                for (int ji = 0; ji < 4; ++ji) a = fmaf(klwm[jo * 4 + ji], kraw[ji], a);
                klin[jo] = a;
            }
            float mn = 0.25f * (klin[0] + klin[1] + klin[2] + klin[3]);
            float d0 = klin[0] - mn, d1 = klin[1] - mn, d2 = klin[2] - mn, d3 = klin[3] - mn;
            float var = 0.25f * (d0 * d0 + d1 * d1 + d2 * d2 + d3 * d3);
            float inv = 1.f / sqrtf(var + 1e-5f);
            float kn[4];
            kn[0] = (d0 * inv * kngv[0] + knbv[0]) * sigk[0];
            kn[1] = (d1 * inv * kngv[1] + knbv[1]) * sigk[1];
            kn[2] = (d2 * inv * kngv[2] + knbv[2]) * sigk[2];
            kn[3] = (d3 * inv * kngv[3] + knbv[3]) * sigk[3];

            const float* qp = Qb + (size_t)f * NTP + t;
            float q0 = qp[0], q1 = qp[1], q2 = qp[2], q3 = qp[3];
            #pragma unroll
            for (int j = 0; j < 4; ++j) {
                s[0 * 4 + j] = fmaf(q0, kn[j], s[0 * 4 + j]);
                s[1 * 4 + j] = fmaf(q1, kn[j], s[1 * 4 + j]);
                s[2 * 4 + j] = fmaf(q2, kn[j], s[2 * 4 + j]);
                s[3 * 4 + j] = fmaf(q3, kn[j], s[3 * 4 + j]);
            }
        }
    }

    // park partials: buf[(w*64+lane)*17 + x]; stride 17 (coprime 32 -> no conflicts)
    {
        float* dst = &buf[(w * 64 + lane) * 17];
        #pragma unroll
        for (int q4 = 0; q4 < 4; ++q4) {
            float4 v = {s[q4 * 4 + 0], s[q4 * 4 + 1], s[q4 * 4 + 2], s[q4 * 4 + 3]};
            *(float4*)(dst + q4 * 4) = v;
        }
    }
    __syncthreads();

    // reduce + quadrant-local softmax: 4 waves, thread = (quadrant, t-lane)
    if (tid < 256) {
        int q4 = tid >> 6;
        int ln = tid & 63;
        int tt = t0 + ln;
        if (tt < NT) {
            float4 a = *(const float4*)&buf[(0 * 64 + ln) * 17 + q4 * 4];
            #pragma unroll
            for (int ww = 1; ww < 16; ++ww) {
                float4 p = *(const float4*)&buf[(ww * 64 + ln) * 17 + q4 * 4];
                a.x += p.x; a.y += p.y; a.z += p.z; a.w += p.w;
            }
            float mx = fmaxf(fmaxf(a.x, a.y), fmaxf(a.z, a.w));
            float e0 = expf(a.x - mx), e1 = expf(a.y - mx);
            float e2 = expf(a.z - mx), e3 = expf(a.w - mx);
            float inv = 1.f / (e0 + e1 + e2 + e3);
            float4 v = {e0 * inv, e1 * inv, e2 * inv, e3 * inv};
            *(float4*)(W + ((size_t)bc * NT + tt) * 16 + q4 * 4) = v;
        }
    }
}

// ---------------------------------------------------------------------------
// complex 4x4 solve, partial pivoting (cabs1), fully unrolled
// ---------------------------------------------------------------------------
__device__ __forceinline__ void csolve4(float Ar[16], float Ai[16],
                                        float br[4], float bi[4],
                                        float wr[4], float wi[4]) {
    #pragma unroll
    for (int col = 0; col < 4; ++col) {
        #pragma unroll
        for (int r = col + 1; r < 4; ++r) {
            float cp = fabsf(Ar[col * 4 + col]) + fabsf(Ai[col * 4 + col]);
            float cr = fabsf(Ar[r * 4 + col]) + fabsf(Ai[r * 4 + col]);
            bool sw = cr > cp;
            #pragma unroll
            for (int m = col; m < 4; ++m) {
                float a0 = Ar[col * 4 + m], a1 = Ar[r * 4 + m];
                Ar[col * 4 + m] = sw ? a1 : a0;
                Ar[r * 4 + m]   = sw ? a0 : a1;
                float c0 = Ai[col * 4 + m], c1 = Ai[r * 4 + m];
                Ai[col * 4 + m] = sw ? c1 : c0;
                Ai[r * 4 + m]   = sw ? c0 : c1;
            }
            float b0 = br[col], b1 = br[r];
            br[col] = sw ? b1 : b0; br[r] = sw ? b0 : b1;
            float d0 = bi[col], d1 = bi[r];
            bi[col] = sw ? d1 : d0; bi[r] = sw ? d0 : d1;
        }
        float pr = Ar[col * 4 + col], pi = Ai[col * 4 + col];
        float den = 1.f / (pr * pr + pi * pi);
        #pragma unroll
        for (int r = col + 1; r < 4; ++r) {
            float nr = Ar[r * 4 + col], ni = Ai[r * 4 + col];
            float fr = (nr * pr + ni * pi) * den;
            float fi = (ni * pr - nr * pi) * den;
            #pragma unroll
            for (int m = col + 1; m < 4; ++m) {
                float tr = Ar[col * 4 + m], ti = Ai[col * 4 + m];
                Ar[r * 4 + m] -= fr * tr - fi * ti;
                Ai[r * 4 + m] -= fr * ti + fi * tr;
            }
            float tr = br[col], ti = bi[col];
            br[r] -= fr * tr - fi * ti;
            bi[r] -= fr * ti + fi * tr;
        }
    }
    #pragma unroll
    for (int col = 3; col >= 0; --col) {
        float sr = br[col], si = bi[col];
        #pragma unroll
        for (int m = col + 1; m < 4; ++m) {
            float tr = Ar[col * 4 + m], ti = Ai[col * 4 + m];
            sr -= tr * wr[m] - ti * wi[m];
            si -= tr * wi[m] + ti * wr[m];
        }
        float pr = Ar[col * 4 + col], pi = Ai[col * 4 + col];
        float den = 1.f / (pr * pr + pi * pi);
        wr[col] = (sr * pr + si * pi) * den;
        wi[col] = (si * pr - sr * pi) * den;
    }
}

// ---------------------------------------------------------------------------
// k4: per (b,f,t): build rank-1 value/out, assemble A,rhs, solve, Wiener sum
// ---------------------------------------------------------------------------
__global__ __launch_bounds__(256) void k4_final(const float* __restrict__ far,
                                                const float* __restrict__ mix,
                                                const float* __restrict__ Wt,
                                                const float* __restrict__ vvec,
                                                float* __restrict__ out) {
    const int t = blockIdx.x * 256 + threadIdx.x;
    const int f = blockIdx.y;
    const int b = blockIdx.z;
    if (t >= NT) return;

    const float* fr  = far + (size_t)(b * 2 + 0) * NF * NT + (size_t)f * NT;
    const float* fim = far + (size_t)(b * 2 + 1) * NF * NT + (size_t)f * NT;
    float ur[4], ui[4];
    #pragma unroll
    for (int d = 0; d < 4; ++d) {
        int tp = t - 3 + d;
        bool ok = tp >= 0;
        ur[d] = ok ? fr[tp] : 0.f;
        ui[d] = ok ? fim[tp] : 0.f;
    }
    float m0 = mix[(size_t)(b * 2 + 0) * NF * NT + (size_t)f * NT + t];
    float m1 = mix[(size_t)(b * 2 + 1) * NF * NT + (size_t)f * NT + t];

    float sv[4];
    #pragma unroll
    for (int i = 0; i < 4; ++i) sv[i] = 1.f / (1.f + expf(-vvec[i]));

    const float* w0p = Wt + ((size_t)(b * 2 + 0) * NT + t) * 16;
    const float* w1p = Wt + ((size_t)(b * 2 + 1) * NT + t) * 16;

    float g0[4], g1[4];
    #pragma unroll
    for (int j = 0; j < 4; ++j) { g0[j] = 0.f; g1[j] = 0.f; }
    #pragma unroll
    for (int i = 0; i < 4; ++i) {
        float a0 = ur[i] * sv[i];
        float a1 = -ui[i] * sv[i];
        #pragma unroll
        for (int j = 0; j < 4; ++j) {
            g0[j] = fmaf(a0, w0p[i * 4 + j], g0[j]);
            g1[j] = fmaf(a1, w1p[i * 4 + j], g1[j]);
        }
    }

    float Ar[16], Ai[16], br[4], bi[4], wr[4], wi[4];
    #pragma unroll
    for (int j = 0; j < 4; ++j) {
        #pragma unroll
        for (int m = 0; m < 4; ++m) {
            float e = (j == m) ? (1.0f + 1e-8f) : 1e-8f;
            Ar[j * 4 + m] = fmaf(ur[m], g0[j], e);
            Ai[j * 4 + m] = fmaf(-ui[m], g1[j], e);
        }
        br[j] = m0 * g0[j];
        bi[j] = m1 * g1[j];
    }

    csolve4(Ar, Ai, br, bi, wr, wi);

    float resr = 0.f, resi = 0.f;
    #pragma unroll
    for (int d = 0; d < 4; ++d) {
        resr += ur[d] * wr[d] - ui[d] * wi[d];
        resi += ur[d] * wi[d] + ui[d] * wr[d];
    }
    out[(size_t)(b * 2 + 0) * NF * NT + (size_t)f * NT + t] = resr;
    out[(size_t)(b * 2 + 1) * NF * NT + (size_t)f * NT + t] = resi;
}

// ---------------------------------------------------------------------------
extern "C" void kernel_launch(void* const* d_in, const int* in_sizes, int n_in,
                              void* d_out, int out_size, void* d_ws, size_t ws_size,
                              hipStream_t stream) {
    const float* far  = (const float*)d_in[0];
    const float* mix  = (const float*)d_in[1];
    const float* kcw  = (const float*)d_in[2];
    const float* kcb  = (const float*)d_in[3];
    const float* qlw  = (const float*)d_in[4];
    const float* qlb  = (const float*)d_in[5];
    const float* qng  = (const float*)d_in[6];
    const float* qnb  = (const float*)d_in[7];
    const float* klw  = (const float*)d_in[8];
    const float* klb  = (const float*)d_in[9];
    const float* kng  = (const float*)d_in[10];
    const float* knb  = (const float*)d_in[11];
    const float* qvec = (const float*)d_in[12];
    const float* kvec = (const float*)d_in[13];
    const float* vvec = (const float*)d_in[14];

    float* Qn = (float*)d_ws;                       // 16*160*NTP
    float* W  = Qn + (size_t)NBC * NF * NTP;        // 16*1000*16
    float* out = (float*)d_out;

    k1_mfma_ln<<<dim3(NBC, 32), 640, 0, stream>>>(far, qlw, qlb, qng, qnb, qvec, Qn);
    k3_attn_v5<<<dim3(NBC, 16), 1024, 0, stream>>>(mix, Qn, kcw, kcb, klw, klb,
                                                   kng, knb, kvec, W);
    k4_final<<<dim3(4, NF, 8), 256, 0, stream>>>(far, mix, W, vvec, out);
}

// Round 9
// 52.057 us; speedup vs baseline: 1.7496x; 1.0851x over previous
//
#include <hip/hip_runtime.h>
#include <math.h>

#define NBC   16          // b*2
#define NF    160
#define NT    1000

typedef __attribute__((ext_vector_type(8))) short short8;
typedef __attribute__((ext_vector_type(4))) float f32x4;

static __device__ __forceinline__ short f2bf(float x) {
    unsigned u = __builtin_bit_cast(unsigned, x);
    unsigned r = (u + 0x7fffu + ((u >> 16) & 1u)) >> 16;
    return (short)r;
}
static __device__ __forceinline__ float bf2f(short s) {
    unsigned u = ((unsigned)(unsigned short)s) << 16;
    return __builtin_bit_cast(float, u);
}

// ---------------------------------------------------------------------------
// k13: FUSED query-proj(MFMA split-bf16) + LayerNorm + key/score/softmax.
// Block = (bc, 64-site t-tile), 1024 thr = 16 waves, 1 block/CU (151 KB LDS).
//   phase 1: stage far cols tq=t0-3..t0+76 -> Xs[160][81]; build bf16 hi/lo
//            B-fragments (80 t-cols = 5 MFMA subtiles)
//   phase 2: 10 waves MFMA (W-frags in VGPRs) -> LN stats -> Qlds[160][81]
//   phase 3: v5 score phase per-lane-site, Q read from LDS (no Qn in HBM!)
//   phase 4: cross-wave reduce + quadrant softmax -> W[bc][t][16]
// LDS pool aliasing: Xs/frags (ph1-2) -> redS/redQ (ph2) -> scorebuf (ph3-4).
// ---------------------------------------------------------------------------
__global__ __launch_bounds__(1024, 4) void k13_fused(const float* __restrict__ far,
                                                     const float* __restrict__ mix,
                                                     const float* __restrict__ qlw,
                                                     const float* __restrict__ qlb,
                                                     const float* __restrict__ qng,
                                                     const float* __restrict__ qnb,
                                                     const float* __restrict__ qvec,
                                                     const float* __restrict__ kcw,
                                                     const float* __restrict__ kcb,
                                                     const float* __restrict__ klw,
                                                     const float* __restrict__ klb,
                                                     const float* __restrict__ kng,
                                                     const float* __restrict__ knb,
                                                     const float* __restrict__ kvec,
                                                     float* __restrict__ W) {
    __shared__ float pool[38720];        // 154880 B, hand-carved
    __shared__ float lnM[80], lnI[80];
    float* Qlds = pool;                          // [160][81] fp32, persistent ph2->ph3
    float* Xs   = pool + 12960;                  // [160][81] staging (ph1)
    short* Bhi  = (short*)(pool + 25920);        // 25 slots x 64 x short8 (25600 B)
    short* Blo  = (short*)(pool + 32320);        // 25600 B
    float* redS = Xs;                            // [80][41]  (aliases Xs, ph2)
    float* redQ = Xs + 3280;
    float* sbuf = Xs;                            // [16][64][17] scorebuf (ph3-4)

    const int bc = blockIdx.x;
    const int t0 = blockIdx.y * 64;
    const int tid = threadIdx.x;
    const int w = __builtin_amdgcn_readfirstlane(tid >> 6);  // 0..15
    const int l = tid & 63;
    const int b = bc >> 1, c = bc & 1;
    const float sgn = c ? -1.f : 1.f;
    const float* Xb = far + (size_t)bc * NF * NT;

    const int row = l & 15;      // A row / D col
    const int kb = l >> 4;       // k-block 0..3

    // ---- A fragments (ql_w rows for this wave's 16 fo), hi/lo bf16 ----
    short8 Ahi[5], Alo[5];
    if (w < 10) {
        #pragma unroll
        for (int fc = 0; fc < 5; ++fc) {
            const float* ap = qlw + (size_t)(16 * w + row) * NF + fc * 32 + kb * 8;
            float4 x0 = *(const float4*)(ap + 0);
            float4 x1 = *(const float4*)(ap + 4);
            float xv[8] = {x0.x, x0.y, x0.z, x0.w, x1.x, x1.y, x1.z, x1.w};
            short8 h, lo;
            #pragma unroll
            for (int j = 0; j < 8; ++j) {
                short hj = f2bf(xv[j]);
                h[j] = hj;
                lo[j] = f2bf(xv[j] - bf2f(hj));
            }
            Ahi[fc] = h; Alo[fc] = lo;
        }
    }

    // ---- phase 1a: stage far cols (160 f x 80 j), j -> tq = t0-3+j ----
    #pragma unroll
    for (int i = 0; i < 13; ++i) {
        int o = tid + i * 1024;
        if (o < 12800) {
            int fi = o / 80, j = o - fi * 80;
            int tq = t0 - 3 + j;
            float v = (tq >= 0 && tq < NT) ? Xb[fi * NT + tq] * sgn : 0.f;
            Xs[fi * 81 + j] = v;
        }
    }
    __syncthreads();

    // ---- phase 1b: build B fragments (25 slots x 64 lanes) ----
    #pragma unroll
    for (int e = 0; e < 2; ++e) {
        int tk = tid + e * 1024;
        if (tk < 1600) {
            int g = tk >> 6;             // tt*5 + fc
            int sl = tk & 63;
            int tt = g / 5, fc = g - 5 * tt;
            int fi0 = fc * 32 + ((sl >> 4) << 3);
            int j0 = tt * 16 + (sl & 15);
            short8 h, lo;
            #pragma unroll
            for (int j = 0; j < 8; ++j) {
                float x = Xs[(fi0 + j) * 81 + j0];
                short hj = f2bf(x);
                h[j] = hj;
                lo[j] = f2bf(x - bf2f(hj));
            }
            *(short8*)&Bhi[tk * 8] = h;
            *(short8*)&Blo[tk * 8] = lo;
        }
    }
    __syncthreads();

    // ---- phase 2: MFMA (10 waves), LN partials into redS/redQ (over Xs) ----
    f32x4 acc0 = {0.f, 0.f, 0.f, 0.f}, acc1 = acc0, acc2 = acc0, acc3 = acc0, acc4 = acc0;
    float qlbv[4], gam[4], bet[4];
    if (w < 10) {
        #pragma unroll
        for (int fc = 0; fc < 5; ++fc) {
            #pragma unroll
            for (int tt = 0; tt < 5; ++tt) {
                short8 bh = *(const short8*)&Bhi[((tt * 5 + fc) * 64 + l) * 8];
                short8 bl = *(const short8*)&Blo[((tt * 5 + fc) * 64 + l) * 8];
                f32x4 a = (tt == 0) ? acc0 : (tt == 1) ? acc1 : (tt == 2) ? acc2 : (tt == 3) ? acc3 : acc4;
                a = __builtin_amdgcn_mfma_f32_16x16x32_bf16(Ahi[fc], bh, a, 0, 0, 0);
                a = __builtin_amdgcn_mfma_f32_16x16x32_bf16(Ahi[fc], bl, a, 0, 0, 0);
                a = __builtin_amdgcn_mfma_f32_16x16x32_bf16(Alo[fc], bh, a, 0, 0, 0);
                if (tt == 0) acc0 = a; else if (tt == 1) acc1 = a; else if (tt == 2) acc2 = a;
                else if (tt == 3) acc3 = a; else acc4 = a;
            }
        }
        #pragma unroll
        for (int r = 0; r < 4; ++r) {
            int fo = 16 * w + kb * 4 + r;
            qlbv[r] = qlb[fo];
            float sq = 1.f / (1.f + expf(-qvec[fo]));
            gam[r] = qng[fo] * sq;
            bet[r] = qnb[fo] * sq;
        }
        #pragma unroll
        for (int tt = 0; tt < 5; ++tt) {
            f32x4 a = (tt == 0) ? acc0 : (tt == 1) ? acc1 : (tt == 2) ? acc2 : (tt == 3) ? acc3 : acc4;
            float v0 = a[0] + qlbv[0], v1 = a[1] + qlbv[1];
            float v2 = a[2] + qlbv[2], v3 = a[3] + qlbv[3];
            int j = tt * 16 + row;
            redS[j * 41 + w * 4 + kb] = v0 + v1 + v2 + v3;
            redQ[j * 41 + w * 4 + kb] = v0 * v0 + v1 * v1 + v2 * v2 + v3 * v3;
        }
    }
    __syncthreads();

    if (tid < 80) {
        float s = 0.f, q = 0.f;
        #pragma unroll 8
        for (int j = 0; j < 40; ++j) {
            s += redS[tid * 41 + j];
            q += redQ[tid * 41 + j];
        }
        float mean = s * (1.f / NF);
        float var = q * (1.f / NF) - mean * mean;
        lnM[tid] = mean;
        lnI[tid] = 1.f / sqrtf(var + 1e-5f);
    }
    __syncthreads();

    if (w < 10) {
        #pragma unroll
        for (int tt = 0; tt < 5; ++tt) {
            f32x4 a = (tt == 0) ? acc0 : (tt == 1) ? acc1 : (tt == 2) ? acc2 : (tt == 3) ? acc3 : acc4;
            int j = tt * 16 + row;
            float mean = lnM[j], inv = lnI[j];
            #pragma unroll
            for (int r = 0; r < 4; ++r) {
                int fo = 16 * w + kb * 4 + r;
                float v = a[r] + qlbv[r];
                Qlds[fo * 81 + j] = (v - mean) * inv * gam[r] + bet[r];
            }
        }
    }
    __syncthreads();

    // ---- phase 3: per-lane-site scores (wave w: f in [10w, 10w+10)) ----
    float kw0[4], kw1[4], kbv[4], klwm[16], klbv[4], kngv[4], knbv[4], sigk[4];
    #pragma unroll
    for (int j = 0; j < 4; ++j) {
        kw0[j] = kcw[(4 * c + j) * 2 + 0];
        kw1[j] = kcw[(4 * c + j) * 2 + 1];
        kbv[j] = kcb[4 * c + j];
        klbv[j] = klb[j];
        kngv[j] = kng[j];
        knbv[j] = knb[j];
        sigk[j] = 0.5f / (1.f + expf(-kvec[j]));   // sigmoid(k_vec)/sqrt(k)
    }
    #pragma unroll
    for (int x = 0; x < 16; ++x) klwm[x] = klw[x];

    const int ts = l;
    const int t = t0 + ts;
    const bool valid = t < NT;

    float s[16];
    #pragma unroll
    for (int x = 0; x < 16; ++x) s[x] = 0.f;

    const float* mix0 = mix + (size_t)(b * 2) * NF * NT;
    const float* mix1 = mix0 + (size_t)NF * NT;
    const int f0 = w * 10;

    if (valid) {
        #pragma unroll
        for (int ff = 0; ff < 10; ++ff) {
            int f = f0 + ff;
            float m0 = mix0[(size_t)f * NT + t];
            float m1 = mix1[(size_t)f * NT + t];
            float kraw[4], klin[4];
            #pragma unroll
            for (int j = 0; j < 4; ++j)
                kraw[j] = fmaf(kw0[j], m0, fmaf(kw1[j], m1, kbv[j]));
            #pragma unroll
            for (int jo = 0; jo < 4; ++jo) {
                float a = klbv[jo];
                #pragma unroll
                for (int ji = 0; ji < 4; ++ji) a = fmaf(klwm[jo * 4 + ji], kraw[ji], a);
                klin[jo] = a;
            }
            float mn = 0.25f * (klin[0] + klin[1] + klin[2] + klin[3]);
            float d0 = klin[0] - mn, d1 = klin[1] - mn, d2 = klin[2] - mn, d3 = klin[3] - mn;
            float var = 0.25f * (d0 * d0 + d1 * d1 + d2 * d2 + d3 * d3);
            float inv = 1.f / sqrtf(var + 1e-5f);
            float kn[4];
            kn[0] = (d0 * inv * kngv[0] + knbv[0]) * sigk[0];
            kn[1] = (d1 * inv * kngv[1] + knbv[1]) * sigk[1];
            kn[2] = (d2 * inv * kngv[2] + knbv[2]) * sigk[2];
            kn[3] = (d3 * inv * kngv[3] + knbv[3]) * sigk[3];

            float q0 = Qlds[f * 81 + ts + 0];
            float q1 = Qlds[f * 81 + ts + 1];
            float q2 = Qlds[f * 81 + ts + 2];
            float q3 = Qlds[f * 81 + ts + 3];
            #pragma unroll
            for (int j = 0; j < 4; ++j) {
                s[0 * 4 + j] = fmaf(q0, kn[j], s[0 * 4 + j]);
                s[1 * 4 + j] = fmaf(q1, kn[j], s[1 * 4 + j]);
                s[2 * 4 + j] = fmaf(q2, kn[j], s[2 * 4 + j]);
                s[3 * 4 + j] = fmaf(q3, kn[j], s[3 * 4 + j]);
            }
        }
    }

    // park partials (stride 17, coprime 32 -> conflict-free); sbuf aliases dead regions
    {
        float* dst = &sbuf[(w * 64 + l) * 17];
        #pragma unroll
        for (int q4 = 0; q4 < 4; ++q4) {
            float4 v = {s[q4 * 4 + 0], s[q4 * 4 + 1], s[q4 * 4 + 2], s[q4 * 4 + 3]};
            *(float4*)(dst + q4 * 4) = v;
        }
    }
    __syncthreads();

    // ---- phase 4: reduce + quadrant softmax + W write ----
    if (tid < 256) {
        int q4 = tid >> 6;
        int ln = tid & 63;
        int tt = t0 + ln;
        if (tt < NT) {
            float4 a = *(const float4*)&sbuf[(0 * 64 + ln) * 17 + q4 * 4];
            #pragma unroll
            for (int ww = 1; ww < 16; ++ww) {
                float4 p = *(const float4*)&sbuf[(ww * 64 + ln) * 17 + q4 * 4];
                a.x += p.x; a.y += p.y; a.z += p.z; a.w += p.w;
            }
            float mx = fmaxf(fmaxf(a.x, a.y), fmaxf(a.z, a.w));
            float e0 = expf(a.x - mx), e1 = expf(a.y - mx);
            float e2 = expf(a.z - mx), e3 = expf(a.w - mx);
            float inv = 1.f / (e0 + e1 + e2 + e3);
            float4 v = {e0 * inv, e1 * inv, e2 * inv, e3 * inv};
            *(float4*)(W + ((size_t)bc * NT + tt) * 16 + q4 * 4) = v;
        }
    }
}

// ---------------------------------------------------------------------------
// complex 4x4 solve, partial pivoting (cabs1), fully unrolled
// ---------------------------------------------------------------------------
__device__ __forceinline__ void csolve4(float Ar[16], float Ai[16],
                                        float br[4], float bi[4],
                                        float wr[4], float wi[4]) {
    #pragma unroll
    for (int col = 0; col < 4; ++col) {
        #pragma unroll
        for (int r = col + 1; r < 4; ++r) {
            float cp = fabsf(Ar[col * 4 + col]) + fabsf(Ai[col * 4 + col]);
            float cr = fabsf(Ar[r * 4 + col]) + fabsf(Ai[r * 4 + col]);
            bool sw = cr > cp;
            #pragma unroll
            for (int m = col; m < 4; ++m) {
                float a0 = Ar[col * 4 + m], a1 = Ar[r * 4 + m];
                Ar[col * 4 + m] = sw ? a1 : a0;
                Ar[r * 4 + m]   = sw ? a0 : a1;
                float c0 = Ai[col * 4 + m], c1 = Ai[r * 4 + m];
                Ai[col * 4 + m] = sw ? c1 : c0;
                Ai[r * 4 + m]   = sw ? c0 : c1;
            }
            float b0 = br[col], b1 = br[r];
            br[col] = sw ? b1 : b0; br[r] = sw ? b0 : b1;
            float d0 = bi[col], d1 = bi[r];
            bi[col] = sw ? d1 : d0; bi[r] = sw ? d0 : d1;
        }
        float pr = Ar[col * 4 + col], pi = Ai[col * 4 + col];
        float den = 1.f / (pr * pr + pi * pi);
        #pragma unroll
        for (int r = col + 1; r < 4; ++r) {
            float nr = Ar[r * 4 + col], ni = Ai[r * 4 + col];
            float fr = (nr * pr + ni * pi) * den;
            float fi = (ni * pr - nr * pi) * den;
            #pragma unroll
            for (int m = col + 1; m < 4; ++m) {
                float tr = Ar[col * 4 + m], ti = Ai[col * 4 + m];
                Ar[r * 4 + m] -= fr * tr - fi * ti;
                Ai[r * 4 + m] -= fr * ti + fi * tr;
            }
            float tr = br[col], ti = bi[col];
            br[r] -= fr * tr - fi * ti;
            bi[r] -= fr * ti + fi * tr;
        }
    }
    #pragma unroll
    for (int col = 3; col >= 0; --col) {
        float sr = br[col], si = bi[col];
        #pragma unroll
        for (int m = col + 1; m < 4; ++m) {
            float tr = Ar[col * 4 + m], ti = Ai[col * 4 + m];
            sr -= tr * wr[m] - ti * wi[m];
            si -= tr * wi[m] + ti * wr[m];
        }
        float pr = Ar[col * 4 + col], pi = Ai[col * 4 + col];
        float den = 1.f / (pr * pr + pi * pi);
        wr[col] = (sr * pr + si * pi) * den;
        wi[col] = (si * pr - sr * pi) * den;
    }
}

// ---------------------------------------------------------------------------
// k4: per (b,f,t): build rank-1 value/out, assemble A,rhs, solve, Wiener sum
// ---------------------------------------------------------------------------
__global__ __launch_bounds__(256) void k4_final(const float* __restrict__ far,
                                                const float* __restrict__ mix,
                                                const float* __restrict__ Wt,
                                                const float* __restrict__ vvec,
                                                float* __restrict__ out) {
    const int t = blockIdx.x * 256 + threadIdx.x;
    const int f = blockIdx.y;
    const int b = blockIdx.z;
    if (t >= NT) return;

    const float* fr  = far + (size_t)(b * 2 + 0) * NF * NT + (size_t)f * NT;
    const float* fim = far + (size_t)(b * 2 + 1) * NF * NT + (size_t)f * NT;
    float ur[4], ui[4];
    #pragma unroll
    for (int d = 0; d < 4; ++d) {
        int tp = t - 3 + d;
        bool ok = tp >= 0;
        ur[d] = ok ? fr[tp] : 0.f;
        ui[d] = ok ? fim[tp] : 0.f;
    }
    float m0 = mix[(size_t)(b * 2 + 0) * NF * NT + (size_t)f * NT + t];
    float m1 = mix[(size_t)(b * 2 + 1) * NF * NT + (size_t)f * NT + t];

    float sv[4];
    #pragma unroll
    for (int i = 0; i < 4; ++i) sv[i] = 1.f / (1.f + expf(-vvec[i]));

    const float* w0p = Wt + ((size_t)(b * 2 + 0) * NT + t) * 16;
    const float* w1p = Wt + ((size_t)(b * 2 + 1) * NT + t) * 16;

    float g0[4], g1[4];
    #pragma unroll
    for (int j = 0; j < 4; ++j) { g0[j] = 0.f; g1[j] = 0.f; }
    #pragma unroll
    for (int i = 0; i < 4; ++i) {
        float a0 = ur[i] * sv[i];
        float a1 = -ui[i] * sv[i];
        #pragma unroll
        for (int j = 0; j < 4; ++j) {
            g0[j] = fmaf(a0, w0p[i * 4 + j], g0[j]);
            g1[j] = fmaf(a1, w1p[i * 4 + j], g1[j]);
        }
    }

    float Ar[16], Ai[16], br[4], bi[4], wr[4], wi[4];
    #pragma unroll
    for (int j = 0; j < 4; ++j) {
        #pragma unroll
        for (int m = 0; m < 4; ++m) {
            float e = (j == m) ? (1.0f + 1e-8f) : 1e-8f;
            Ar[j * 4 + m] = fmaf(ur[m], g0[j], e);
            Ai[j * 4 + m] = fmaf(-ui[m], g1[j], e);
        }
        br[j] = m0 * g0[j];
        bi[j] = m1 * g1[j];
    }

    csolve4(Ar, Ai, br, bi, wr, wi);

    float resr = 0.f, resi = 0.f;
    #pragma unroll
    for (int d = 0; d < 4; ++d) {
        resr += ur[d] * wr[d] - ui[d] * wi[d];
        resi += ur[d] * wi[d] + ui[d] * wr[d];
    }
    out[(size_t)(b * 2 + 0) * NF * NT + (size_t)f * NT + t] = resr;
    out[(size_t)(b * 2 + 1) * NF * NT + (size_t)f * NT + t] = resi;
}

// ---------------------------------------------------------------------------
extern "C" void kernel_launch(void* const* d_in, const int* in_sizes, int n_in,
                              void* d_out, int out_size, void* d_ws, size_t ws_size,
                              hipStream_t stream) {
    const float* far  = (const float*)d_in[0];
    const float* mix  = (const float*)d_in[1];
    const float* kcw  = (const float*)d_in[2];
    const float* kcb  = (const float*)d_in[3];
    const float* qlw  = (const float*)d_in[4];
    const float* qlb  = (const float*)d_in[5];
    const float* qng  = (const float*)d_in[6];
    const float* qnb  = (const float*)d_in[7];
    const float* klw  = (const float*)d_in[8];
    const float* klb  = (const float*)d_in[9];
    const float* kng  = (const float*)d_in[10];
    const float* knb  = (const float*)d_in[11];
    const float* qvec = (const float*)d_in[12];
    const float* kvec = (const float*)d_in[13];
    const float* vvec = (const float*)d_in[14];

    float* W = (float*)d_ws;                 // 16*1000*16 floats
    float* out = (float*)d_out;

    k13_fused<<<dim3(NBC, 16), 1024, 0, stream>>>(far, mix, qlw, qlb, qng, qnb, qvec,
                                                  kcw, kcb, klw, klb, kng, knb, kvec, W);
    k4_final<<<dim3(4, NF, 8), 256, 0, stream>>>(far, mix, W, vvec, out);
}